// Round 2
// baseline (3997.203 us; speedup 1.0000x reference)
//
#include <hip/hip_runtime.h>

#define D_ 128
#define BATCH_ 65536

// ---------------- utility ----------------
__global__ void k_zero32(uint32_t* p, long long n) {
    long long i = (long long)blockIdx.x * blockDim.x + threadIdx.x;
    long long st = (long long)gridDim.x * blockDim.x;
    for (; i < n; i += st) p[i] = 0u;
}

__global__ void k_sentinel(float* p, long long n) {
    long long i = (long long)blockIdx.x * blockDim.x + threadIdx.x;
    long long st = (long long)gridDim.x * blockDim.x;
    for (; i < n; i += st) p[i] = -12345.0f;
}

// ---------------- CSR build (edge_index is int32 on device) ----------------
__global__ void k_count(const int* __restrict__ ei, int* __restrict__ cnt, int N, int E) {
    long long i = (long long)blockIdx.x * blockDim.x + threadIdx.x;
    long long st = (long long)gridDim.x * blockDim.x;
    long long tot = 3LL * E;
    for (; i < tot; i += st) {
        int t = (int)(i / E);
        int w = (int)(i - (long long)t * E);
        int dst = ei[(long long)t * 2 * E + E + w];
        atomicAdd(&cnt[t * N + dst], 1);
    }
}

__global__ void k_dinv(const int* __restrict__ cnt, float* __restrict__ dinv, int L) {
    int i = blockIdx.x * blockDim.x + threadIdx.x;
    if (i < L) dinv[i] = rsqrtf((float)cnt[i] + 1.0f);
}

__global__ void k_scan1(const int* __restrict__ in, int* __restrict__ excl,
                        int* __restrict__ bsum, int L) {
    __shared__ int s[512];
    int t = threadIdx.x;
    int g = blockIdx.x * 512 + t;
    int v = (g < L) ? in[g] : 0;
    s[t] = v;
    __syncthreads();
    for (int off = 1; off < 512; off <<= 1) {
        int a = (t >= off) ? s[t - off] : 0;
        __syncthreads();
        s[t] += a;
        __syncthreads();
    }
    if (g < L) excl[g] = s[t] - v;
    if (t == 511) bsum[blockIdx.x] = s[511];
}

__global__ void k_scan2(const int* __restrict__ bsum, int* __restrict__ bscan, int nb) {
    __shared__ int s[1024];
    int t = threadIdx.x;
    int v = (t < nb) ? bsum[t] : 0;
    s[t] = v;
    __syncthreads();
    for (int off = 1; off < 1024; off <<= 1) {
        int a = (t >= off) ? s[t - off] : 0;
        __syncthreads();
        s[t] += a;
        __syncthreads();
    }
    bscan[t] = s[t] - v;  // exclusive
}

__global__ void k_scan3(int* __restrict__ excl, const int* __restrict__ bscan, int L, int total) {
    int g = blockIdx.x * blockDim.x + threadIdx.x;
    if (g < L) excl[g] += bscan[g >> 9];
    if (g == 0) excl[L] = total;
}

__global__ void k_fill(const int* __restrict__ ei, const int* __restrict__ rowstart,
                       int* __restrict__ cur, int* __restrict__ csr, int N, int E) {
    long long i = (long long)blockIdx.x * blockDim.x + threadIdx.x;
    long long st = (long long)gridDim.x * blockDim.x;
    long long tot = 3LL * E;
    for (; i < tot; i += st) {
        int t = (int)(i / E);
        int w = (int)(i - (long long)t * E);
        int src = ei[(long long)t * 2 * E + w];
        int dst = ei[(long long)t * 2 * E + E + w];
        int r = t * N + dst;
        int pos = rowstart[r] + atomicAdd(&cur[r], 1);
        csr[pos] = src;
    }
}

// ---------------- dense GEMM: out = [relu](gather(in) @ W [+ bias]) ----------------
// 64x64 tile per block, 256 threads, 4x4 acc per thread, W staged in two 64-row halves.
__global__ __launch_bounds__(256) void k_gemm(const float* __restrict__ in,
                                              const int* __restrict__ gidx,
                                              const float* __restrict__ W,
                                              const float* __restrict__ bias,
                                              float* __restrict__ out, int n, int relu) {
    __shared__ float Xs[64][136];
    __shared__ float Ws[64][64];
    int bid = blockIdx.x;
    int rt = bid >> 1, cb = bid & 1;
    int row0 = rt << 6;
    int t = threadIdx.x;
#pragma unroll
    for (int i = 0; i < 8; i++) {
        int f4 = t + (i << 8);
        int r = f4 >> 5, c4 = (f4 & 31) << 2;
        int gr = row0 + r;
        float4 v = make_float4(0.f, 0.f, 0.f, 0.f);
        if (gr < n) {
            long long srow = gidx ? (long long)gidx[gr] : (long long)gr;
            v = *(const float4*)(in + srow * D_ + c4);
        }
        *(float4*)&Xs[r][c4] = v;
    }
    int r0 = (t >> 4) << 2;
    int c0 = (t & 15) << 2;
    float acc[4][4] = {};
#pragma unroll
    for (int half = 0; half < 2; half++) {
        __syncthreads();
#pragma unroll
        for (int i = 0; i < 4; i++) {
            int f4 = t + (i << 8);
            int k = f4 >> 4, c4 = (f4 & 15) << 2;
            *(float4*)&Ws[k][c4] = *(const float4*)(W + (size_t)((half << 6) + k) * D_ + (cb << 6) + c4);
        }
        __syncthreads();
#pragma unroll 4
        for (int k0 = 0; k0 < 64; k0 += 4) {
            float a_[4][4], b_[4][4];
#pragma unroll
            for (int rr = 0; rr < 4; rr++) {
                float4 v = *(float4*)&Xs[r0 + rr][(half << 6) + k0];
                a_[rr][0] = v.x; a_[rr][1] = v.y; a_[rr][2] = v.z; a_[rr][3] = v.w;
            }
#pragma unroll
            for (int kk = 0; kk < 4; kk++) {
                float4 v = *(float4*)&Ws[k0 + kk][c0];
                b_[kk][0] = v.x; b_[kk][1] = v.y; b_[kk][2] = v.z; b_[kk][3] = v.w;
            }
#pragma unroll
            for (int kk = 0; kk < 4; kk++)
#pragma unroll
                for (int rr = 0; rr < 4; rr++)
#pragma unroll
                    for (int cc = 0; cc < 4; cc++)
                        acc[rr][cc] = fmaf(a_[rr][kk], b_[kk][cc], acc[rr][cc]);
        }
    }
    int gcb = (cb << 6) + c0;
#pragma unroll
    for (int rr = 0; rr < 4; rr++) {
        int gr = row0 + r0 + rr;
        if (gr >= n) continue;
        float4 o;
        o.x = acc[rr][0]; o.y = acc[rr][1]; o.z = acc[rr][2]; o.w = acc[rr][3];
        if (bias) { o.x += bias[gcb]; o.y += bias[gcb + 1]; o.z += bias[gcb + 2]; o.w += bias[gcb + 3]; }
        if (relu) {
            o.x = fmaxf(o.x, 0.f); o.y = fmaxf(o.y, 0.f);
            o.z = fmaxf(o.z, 0.f); o.w = fmaxf(o.w, 0.f);
        }
        *(float4*)(out + (size_t)gr * D_ + gcb) = o;
    }
}

// ---------------- GCN aggregate (gather CSR), optional copy of rows<B to out2 ----------------
// out[i] = relu( (sum_j g[src_j]*dinv[src_j] + g[i]*dinv[i]) * dinv[i] + bias )
__global__ __launch_bounds__(256) void k_spmm(const float* __restrict__ g,
                                              const int* __restrict__ csr,
                                              const int* __restrict__ rowstart,
                                              const float* __restrict__ dinv,
                                              const float* __restrict__ bias,
                                              float* __restrict__ out,
                                              float* __restrict__ out2, int n) {
    int gw = (int)((blockIdx.x * (long long)blockDim.x + threadIdx.x) >> 6);
    int lane = threadIdx.x & 63;
    if (gw >= n) return;
    int s0 = rowstart[gw], s1 = rowstart[gw + 1];
    float di = dinv[gw];
    size_t base = (size_t)gw * D_ + (lane << 1);
    float2 gi = *(const float2*)(g + base);
    float ax = gi.x * di, ay = gi.y * di;
    for (int j = s0; j < s1; j++) {
        int s = csr[j];
        float w = dinv[s];
        float2 gv = *(const float2*)(g + (size_t)s * D_ + (lane << 1));
        ax = fmaf(gv.x, w, ax);
        ay = fmaf(gv.y, w, ay);
    }
    float2 b = *(const float2*)(bias + (lane << 1));
    float2 o = make_float2(fmaxf(fmaf(ax, di, b.x), 0.f), fmaxf(fmaf(ay, di, b.y), 0.f));
    *(float2*)(out + base) = o;
    if (out2 && gw < BATCH_) *(float2*)(out2 + base) = o;
}

// ---------------- semantic attention partial scores for ONE type ----------------
// per row r of z (n rows): s_r = sum_a q[a]*tanh((z_r @ W_sem)[a] + b_sem[a])
__global__ __launch_bounds__(256) void k_att(const float* __restrict__ z,
                                             const float* __restrict__ Wsem,
                                             const float* __restrict__ bsem,
                                             const float* __restrict__ q,
                                             float* __restrict__ att_part, int n, int ttype) {
    __shared__ float Xs[64][136];
    __shared__ float Ws[64][64];
    __shared__ float sblk;
    int bid = blockIdx.x;
    int rt = bid >> 1, cb = bid & 1;
    int row0 = rt << 6;
    int t = threadIdx.x;
    if (t == 0) sblk = 0.f;
#pragma unroll
    for (int i = 0; i < 8; i++) {
        int f4 = t + (i << 8);
        int r = f4 >> 5, c4 = (f4 & 31) << 2;
        int gr = row0 + r;
        float4 v = make_float4(0.f, 0.f, 0.f, 0.f);
        if (gr < n) v = *(const float4*)(z + (size_t)gr * D_ + c4);
        *(float4*)&Xs[r][c4] = v;
    }
    int r0 = (t >> 4) << 2;
    int c0 = (t & 15) << 2;
    float acc[4][4] = {};
#pragma unroll
    for (int half = 0; half < 2; half++) {
        __syncthreads();
#pragma unroll
        for (int i = 0; i < 4; i++) {
            int f4 = t + (i << 8);
            int k = f4 >> 4, c4 = (f4 & 15) << 2;
            *(float4*)&Ws[k][c4] = *(const float4*)(Wsem + (size_t)((half << 6) + k) * D_ + (cb << 6) + c4);
        }
        __syncthreads();
#pragma unroll 4
        for (int k0 = 0; k0 < 64; k0 += 4) {
            float a_[4][4], b_[4][4];
#pragma unroll
            for (int rr = 0; rr < 4; rr++) {
                float4 v = *(float4*)&Xs[r0 + rr][(half << 6) + k0];
                a_[rr][0] = v.x; a_[rr][1] = v.y; a_[rr][2] = v.z; a_[rr][3] = v.w;
            }
#pragma unroll
            for (int kk = 0; kk < 4; kk++) {
                float4 v = *(float4*)&Ws[k0 + kk][c0];
                b_[kk][0] = v.x; b_[kk][1] = v.y; b_[kk][2] = v.z; b_[kk][3] = v.w;
            }
#pragma unroll
            for (int kk = 0; kk < 4; kk++)
#pragma unroll
                for (int rr = 0; rr < 4; rr++)
#pragma unroll
                    for (int cc = 0; cc < 4; cc++)
                        acc[rr][cc] = fmaf(a_[rr][kk], b_[kk][cc], acc[rr][cc]);
        }
    }
    int gcb = (cb << 6) + c0;
    float q0 = q[gcb], q1 = q[gcb + 1], q2 = q[gcb + 2], q3 = q[gcb + 3];
    float e0 = bsem[gcb], e1 = bsem[gcb + 1], e2 = bsem[gcb + 2], e3 = bsem[gcb + 3];
    int tc = t & 15;
    float s_[4];
#pragma unroll
    for (int rr = 0; rr < 4; rr++) {
        float s = q0 * tanhf(acc[rr][0] + e0) + q1 * tanhf(acc[rr][1] + e1) +
                  q2 * tanhf(acc[rr][2] + e2) + q3 * tanhf(acc[rr][3] + e3);
#pragma unroll
        for (int m = 1; m < 16; m <<= 1) s += __shfl_xor(s, m, 64);
        s_[rr] = s;
    }
    if (tc == 0) {
#pragma unroll
        for (int rr = 0; rr < 4; rr++) {
            if (row0 + r0 + rr < n) atomicAdd(&sblk, s_[rr]);
        }
    }
    __syncthreads();
    if (t == 0) atomicAdd(&att_part[((bid & 63) << 2) + ttype], sblk);
}

__global__ void k_attw(const float* __restrict__ att_part, float* __restrict__ att_w, float invN) {
    __shared__ float sb[3];
    int t = threadIdx.x;
    if (t < 3) {
        float s = 0.f;
        for (int i = 0; i < 64; i++) s += att_part[(i << 2) + t];
        sb[t] = s * invN;
    }
    __syncthreads();
    if (t == 0) {
        float m = fmaxf(sb[0], fmaxf(sb[1], sb[2]));
        float x0 = expf(sb[0] - m), x1 = expf(sb[1] - m), x2 = expf(sb[2] - m);
        float inv = 1.f / (x0 + x1 + x2);
        att_w[0] = x0 * inv; att_w[1] = x1 * inv; att_w[2] = x2 * inv;
    }
}

// ---------------- pos: column sums of combined rows (no materialization) ----------------
__global__ __launch_bounds__(256) void k_colsum(const float* __restrict__ Zb, size_t BD,
                                                const float* __restrict__ att_w,
                                                float* __restrict__ colsum) {
    int c2 = threadIdx.x & 63;
    int rg = threadIdx.x >> 6;
    int nbase = blockIdx.x << 7;  // 128 rows per block, 512 blocks = 65536 rows
    float w0 = att_w[0], w1 = att_w[1], w2 = att_w[2];
    float csx = 0.f, csy = 0.f;
    for (int i = rg; i < 128; i += 4) {
        size_t off = (size_t)(nbase + i) * D_ + (c2 << 1);
        float2 z0 = *(const float2*)(Zb + off);
        float2 z1 = *(const float2*)(Zb + BD + off);
        float2 z2 = *(const float2*)(Zb + 2 * BD + off);
        csx += w0 * z0.x + w1 * z1.x + w2 * z2.x;
        csy += w0 * z0.y + w1 * z1.y + w2 * z2.y;
    }
    __shared__ float red[4][128];
    red[rg][c2 << 1] = csx;
    red[rg][(c2 << 1) + 1] = csy;
    __syncthreads();
    if (rg == 0) {
        float sx = red[0][c2 << 1] + red[1][c2 << 1] + red[2][c2 << 1] + red[3][c2 << 1];
        float sy = red[0][(c2 << 1) + 1] + red[1][(c2 << 1) + 1] + red[2][(c2 << 1) + 1] + red[3][(c2 << 1) + 1];
        atomicAdd(&colsum[c2 << 1], sx);
        atomicAdd(&colsum[(c2 << 1) + 1], sy);
    }
}

__global__ void k_summary_c(const float* __restrict__ colsum, const float* __restrict__ sv,
                            const float* __restrict__ Wd, float* __restrict__ cvec,
                            float* __restrict__ out_summary) {
    __shared__ float sl[128];
    int t = threadIdx.x;  // 128 threads
    float s = 0.5f * (sv[t] + colsum[t] * (1.0f / (float)BATCH_));
    sl[t] = s;
    out_summary[t] = s;
    __syncthreads();
    float a = 0.f;
    for (int j = 0; j < 128; j++) a = fmaf(Wd[t * D_ + j], sl[j], a);
    cvec[t] = a;
}

// ---------------- score: combine z_t[:B] rows on the fly, dot with c ----------------
__global__ __launch_bounds__(256) void k_cscore(const float* __restrict__ Zb, size_t BD,
                                                const float* __restrict__ att_w,
                                                const float* __restrict__ c,
                                                const float* __restrict__ bd,
                                                float* __restrict__ out, int B) {
    int gw = (int)((blockIdx.x * (long long)blockDim.x + threadIdx.x) >> 6);
    int lane = threadIdx.x & 63;
    if (gw >= B) return;
    size_t off = (size_t)gw * D_ + (lane << 1);
    float w0 = att_w[0], w1 = att_w[1], w2 = att_w[2];
    float2 z0 = *(const float2*)(Zb + off);
    float2 z1 = *(const float2*)(Zb + BD + off);
    float2 z2 = *(const float2*)(Zb + 2 * BD + off);
    float vx = w0 * z0.x + w1 * z1.x + w2 * z2.x;
    float vy = w0 * z0.y + w1 * z1.y + w2 * z2.y;
    float2 cc = *(const float2*)(c + (lane << 1));
    float a = vx * cc.x + vy * cc.y;
#pragma unroll
    for (int m = 1; m < 64; m <<= 1) a += __shfl_xor(a, m, 64);
    if (lane == 0) out[gw] = a + bd[0];
}

// ---------------- host launcher ----------------
extern "C" void kernel_launch(void* const* d_in, const int* in_sizes, int n_in,
                              void* d_out, int out_size, void* d_ws, size_t ws_size,
                              hipStream_t stream) {
    const float* x      = (const float*)d_in[0];
    const int*   ei     = (const int*)d_in[1];    // int32 on device
    const int*   perm   = (const int*)d_in[2];    // int32 on device
    const float* sv     = (const float*)d_in[3];
    const float* W_lin  = (const float*)d_in[5];
    const float* b_lin  = (const float*)d_in[6];
    const float* W1     = (const float*)d_in[7];
    const float* b1     = (const float*)d_in[8];
    const float* W2     = (const float*)d_in[9];
    const float* b2     = (const float*)d_in[10];
    const float* W_sem  = (const float*)d_in[11];
    const float* b_sem  = (const float*)d_in[12];
    const float* q_sem  = (const float*)d_in[13];
    const float* W_disc = (const float*)d_in[14];
    const float* b_disc = (const float*)d_in[15];
    float* out = (float*)d_out;

    int N = in_sizes[0] / D_;
    int E = in_sizes[1] / 6;
    int L = 3 * N;
    size_t ND = (size_t)N * D_;
    size_t BD = (size_t)BATCH_ * D_;
    int B = BATCH_;

    char* ws = (char*)d_ws;
    size_t o = 0;
    auto alloc = [&](size_t bytes) -> char* {
        char* p = ws + o;
        o = (o + bytes + 255) & ~(size_t)255;
        return p;
    };
    // common small buffers first
    float* dinv     = (float*)alloc((size_t)L * 4);
    int*   cnt      = (int*)alloc((size_t)L * 4);
    int*   rowstart = (int*)alloc(((size_t)L + 1) * 4);
    int*   csr      = (int*)alloc((size_t)3 * E * 4);
    int*   bsum     = (int*)alloc(1024 * 4);
    int*   bscan    = (int*)alloc(1024 * 4);
    float* att_part = (float*)alloc(256 * 4);
    float* att_w    = (float*)alloc(16 * 4);   // [0..2]=pos, [8..10]=neg
    float* colsum   = (float*)alloc(128 * 4);
    float* cvec     = (float*)alloc(128 * 4);
    float* Zb       = (float*)alloc(3 * BD * 4);   // z_t[:B] per type
    size_t o_small = o;
    // full mode: A + G + H ; lean mode: G + H only (recompute x0 per type)
    float* G = (float*)alloc(ND * 4);
    float* H = (float*)alloc(ND * 4);
    size_t o_lean = o;
    float* A = (float*)alloc(ND * 4);
    size_t o_full = o;

    int mode;  // 0=full, 1=lean, 2=sentinel
    if (o_full <= ws_size) mode = 0;
    else if (o_lean <= ws_size) mode = 1;
    else mode = 2;
    if (mode == 2) {
        k_sentinel<<<256, 256, 0, stream>>>(out, out_size);
        return;
    }
    (void)o_small;

    // ---- CSR build (by destination), per edge type ----
    k_zero32<<<256, 256, 0, stream>>>((uint32_t*)cnt, L);
    k_count<<<2048, 256, 0, stream>>>(ei, cnt, N, E);
    k_dinv<<<(L + 255) / 256, 256, 0, stream>>>(cnt, dinv, L);
    int nb = (L + 511) / 512;
    k_scan1<<<nb, 512, 0, stream>>>(cnt, rowstart, bsum, L);
    k_scan2<<<1, 1024, 0, stream>>>(bsum, bscan, nb);
    k_scan3<<<(L + 255) / 256, 256, 0, stream>>>(rowstart, bscan, L, 3 * E);
    k_zero32<<<256, 256, 0, stream>>>((uint32_t*)cnt, L);
    k_fill<<<2048, 256, 0, stream>>>(ei, rowstart, cnt, csr, N, E);

    int gemm_grid = ((N + 63) / 64) * 2;
    int spmm_grid = (N + 3) / 4;
    int scoreB_grid = (B + 3) / 4;

    for (int br = 0; br < 2; br++) {
        const int* gidx = br ? perm : nullptr;
        float* aw = att_w + br * 8;
        if (mode == 0) {
            // x0 = relu( gather(x) @ W_lin + b_lin ), kept for all 3 types
            k_gemm<<<gemm_grid, 256, 0, stream>>>(x, gidx, W_lin, b_lin, A, N, 1);
        }
        k_zero32<<<1, 256, 0, stream>>>((uint32_t*)att_part, 256);
        for (int t3 = 0; t3 < 3; t3++) {
            const int* rs = rowstart + (size_t)t3 * N;
            const float* dv = dinv + (size_t)t3 * N;
            float* Zbt = Zb + (size_t)t3 * BD;
            if (mode == 0) {
                k_gemm<<<gemm_grid, 256, 0, stream>>>(A, nullptr, W1, nullptr, G, N, 0);
                k_spmm<<<spmm_grid, 256, 0, stream>>>(G, csr, rs, dv, b1, H, nullptr, N);   // h1
                k_gemm<<<gemm_grid, 256, 0, stream>>>(H, nullptr, W2, nullptr, G, N, 0);
                k_spmm<<<spmm_grid, 256, 0, stream>>>(G, csr, rs, dv, b2, H, Zbt, N);       // z_t
                k_att<<<gemm_grid, 256, 0, stream>>>(H, W_sem, b_sem, q_sem, att_part, N, t3);
            } else {
                k_gemm<<<gemm_grid, 256, 0, stream>>>(x, gidx, W_lin, b_lin, G, N, 1);      // x0
                k_gemm<<<gemm_grid, 256, 0, stream>>>(G, nullptr, W1, nullptr, H, N, 0);
                k_spmm<<<spmm_grid, 256, 0, stream>>>(H, csr, rs, dv, b1, G, nullptr, N);   // h1
                k_gemm<<<gemm_grid, 256, 0, stream>>>(G, nullptr, W2, nullptr, H, N, 0);
                k_spmm<<<spmm_grid, 256, 0, stream>>>(H, csr, rs, dv, b2, G, Zbt, N);       // z_t
                k_att<<<gemm_grid, 256, 0, stream>>>(G, W_sem, b_sem, q_sem, att_part, N, t3);
            }
        }
        k_attw<<<1, 64, 0, stream>>>(att_part, aw, 1.0f / (float)N);
        if (br == 0) {
            k_zero32<<<1, 256, 0, stream>>>((uint32_t*)colsum, 128);
            k_colsum<<<512, 256, 0, stream>>>(Zb, BD, aw, colsum);
            k_summary_c<<<1, 128, 0, stream>>>(colsum, sv, W_disc, cvec, out + 2 * (size_t)B);
            k_cscore<<<scoreB_grid, 256, 0, stream>>>(Zb, BD, aw, cvec, b_disc, out, B);
        } else {
            k_cscore<<<scoreB_grid, 256, 0, stream>>>(Zb, BD, aw, cvec, b_disc, out + B, B);
        }
    }
}

// Round 3
// 3420.660 us; speedup vs baseline: 1.1685x; 1.1685x over previous
//
#include <hip/hip_runtime.h>

#define D_ 128
#define BATCH_ 65536

// ---------------- utility ----------------
__global__ void k_zero32(uint32_t* p, long long n) {
    long long i = (long long)blockIdx.x * blockDim.x + threadIdx.x;
    long long st = (long long)gridDim.x * blockDim.x;
    for (; i < n; i += st) p[i] = 0u;
}

__global__ void k_sentinel(float* p, long long n) {
    long long i = (long long)blockIdx.x * blockDim.x + threadIdx.x;
    long long st = (long long)gridDim.x * blockDim.x;
    for (; i < n; i += st) p[i] = -12345.0f;
}

// ---------------- CSR build (edge_index is int32 on device) ----------------
__global__ void k_count(const int* __restrict__ ei, int* __restrict__ cnt, int N, int E) {
    long long i = (long long)blockIdx.x * blockDim.x + threadIdx.x;
    long long st = (long long)gridDim.x * blockDim.x;
    long long tot = 3LL * E;
    for (; i < tot; i += st) {
        int t = (int)(i / E);
        int w = (int)(i - (long long)t * E);
        int dst = ei[(long long)t * 2 * E + E + w];
        atomicAdd(&cnt[t * N + dst], 1);
    }
}

__global__ void k_dinv(const int* __restrict__ cnt, float* __restrict__ dinv, int L) {
    int i = blockIdx.x * blockDim.x + threadIdx.x;
    if (i < L) dinv[i] = rsqrtf((float)cnt[i] + 1.0f);
}

__global__ void k_scan1(const int* __restrict__ in, int* __restrict__ excl,
                        int* __restrict__ bsum, int L) {
    __shared__ int s[512];
    int t = threadIdx.x;
    int g = blockIdx.x * 512 + t;
    int v = (g < L) ? in[g] : 0;
    s[t] = v;
    __syncthreads();
    for (int off = 1; off < 512; off <<= 1) {
        int a = (t >= off) ? s[t - off] : 0;
        __syncthreads();
        s[t] += a;
        __syncthreads();
    }
    if (g < L) excl[g] = s[t] - v;
    if (t == 511) bsum[blockIdx.x] = s[511];
}

__global__ void k_scan2(const int* __restrict__ bsum, int* __restrict__ bscan, int nb) {
    __shared__ int s[1024];
    int t = threadIdx.x;
    int v = (t < nb) ? bsum[t] : 0;
    s[t] = v;
    __syncthreads();
    for (int off = 1; off < 1024; off <<= 1) {
        int a = (t >= off) ? s[t - off] : 0;
        __syncthreads();
        s[t] += a;
        __syncthreads();
    }
    bscan[t] = s[t] - v;  // exclusive
}

__global__ void k_scan3(int* __restrict__ excl, const int* __restrict__ bscan, int L, int total) {
    int g = blockIdx.x * blockDim.x + threadIdx.x;
    if (g < L) excl[g] += bscan[g >> 9];
    if (g == 0) excl[L] = total;
}

__global__ void k_fill(const int* __restrict__ ei, const int* __restrict__ rowstart,
                       int* __restrict__ cur, int* __restrict__ csr, int N, int E) {
    long long i = (long long)blockIdx.x * blockDim.x + threadIdx.x;
    long long st = (long long)gridDim.x * blockDim.x;
    long long tot = 3LL * E;
    for (; i < tot; i += st) {
        int t = (int)(i / E);
        int w = (int)(i - (long long)t * E);
        int src = ei[(long long)t * 2 * E + w];
        int dst = ei[(long long)t * 2 * E + E + w];
        int r = t * N + dst;
        int pos = rowstart[r] + atomicAdd(&cur[r], 1);
        csr[pos] = src;
    }
}

// ---------------- dense GEMM: out = [relu](gather(in) @ W [+ bias]) [* scale[row]] ----------------
// 64x64 tile per block, 256 threads, 4x4 acc per thread, W staged in two 64-row halves.
__global__ __launch_bounds__(256) void k_gemm(const float* __restrict__ in,
                                              const int* __restrict__ gidx,
                                              const float* __restrict__ W,
                                              const float* __restrict__ bias,
                                              const float* __restrict__ scale,
                                              float* __restrict__ out, int n, int relu) {
    __shared__ float Xs[64][136];
    __shared__ float Ws[64][64];
    int bid = blockIdx.x;
    int rt = bid >> 1, cb = bid & 1;
    int row0 = rt << 6;
    int t = threadIdx.x;
#pragma unroll
    for (int i = 0; i < 8; i++) {
        int f4 = t + (i << 8);
        int r = f4 >> 5, c4 = (f4 & 31) << 2;
        int gr = row0 + r;
        float4 v = make_float4(0.f, 0.f, 0.f, 0.f);
        if (gr < n) {
            long long srow = gidx ? (long long)gidx[gr] : (long long)gr;
            v = *(const float4*)(in + srow * D_ + c4);
        }
        *(float4*)&Xs[r][c4] = v;
    }
    int r0 = (t >> 4) << 2;
    int c0 = (t & 15) << 2;
    float acc[4][4] = {};
#pragma unroll
    for (int half = 0; half < 2; half++) {
        __syncthreads();
#pragma unroll
        for (int i = 0; i < 4; i++) {
            int f4 = t + (i << 8);
            int k = f4 >> 4, c4 = (f4 & 15) << 2;
            *(float4*)&Ws[k][c4] = *(const float4*)(W + (size_t)((half << 6) + k) * D_ + (cb << 6) + c4);
        }
        __syncthreads();
#pragma unroll 4
        for (int k0 = 0; k0 < 64; k0 += 4) {
            float a_[4][4], b_[4][4];
#pragma unroll
            for (int rr = 0; rr < 4; rr++) {
                float4 v = *(float4*)&Xs[r0 + rr][(half << 6) + k0];
                a_[rr][0] = v.x; a_[rr][1] = v.y; a_[rr][2] = v.z; a_[rr][3] = v.w;
            }
#pragma unroll
            for (int kk = 0; kk < 4; kk++) {
                float4 v = *(float4*)&Ws[k0 + kk][c0];
                b_[kk][0] = v.x; b_[kk][1] = v.y; b_[kk][2] = v.z; b_[kk][3] = v.w;
            }
#pragma unroll
            for (int kk = 0; kk < 4; kk++)
#pragma unroll
                for (int rr = 0; rr < 4; rr++)
#pragma unroll
                    for (int cc = 0; cc < 4; cc++)
                        acc[rr][cc] = fmaf(a_[rr][kk], b_[kk][cc], acc[rr][cc]);
        }
    }
    int gcb = (cb << 6) + c0;
#pragma unroll
    for (int rr = 0; rr < 4; rr++) {
        int gr = row0 + r0 + rr;
        if (gr >= n) continue;
        float4 o;
        o.x = acc[rr][0]; o.y = acc[rr][1]; o.z = acc[rr][2]; o.w = acc[rr][3];
        if (bias) { o.x += bias[gcb]; o.y += bias[gcb + 1]; o.z += bias[gcb + 2]; o.w += bias[gcb + 3]; }
        if (relu) {
            o.x = fmaxf(o.x, 0.f); o.y = fmaxf(o.y, 0.f);
            o.z = fmaxf(o.z, 0.f); o.w = fmaxf(o.w, 0.f);
        }
        if (scale) {
            float sc = scale[gr];
            o.x *= sc; o.y *= sc; o.z *= sc; o.w *= sc;
        }
        *(float4*)(out + (size_t)gr * D_ + gcb) = o;
    }
}

// ---------------- GCN aggregate (gather CSR), g rows pre-scaled by dinv[src] ----------------
// out[i] = relu( (sum_j g[src_j] + g[i]) * dinv[i] + bias )     (g already = h*dinv)
// unrolled x8 for memory-level parallelism (gathers are L3-resident, latency-bound).
__global__ __launch_bounds__(256) void k_spmm(const float* __restrict__ g,
                                              const int* __restrict__ csr,
                                              const int* __restrict__ rowstart,
                                              const float* __restrict__ dinv,
                                              const float* __restrict__ bias,
                                              float* __restrict__ out,
                                              float* __restrict__ out2, int n) {
    int gw = (int)((blockIdx.x * (long long)blockDim.x + threadIdx.x) >> 6);
    int lane = threadIdx.x & 63;
    if (gw >= n) return;
    int s0 = rowstart[gw], s1 = rowstart[gw + 1];
    float di = dinv[gw];
    size_t co = (size_t)(lane << 1);
    size_t base = (size_t)gw * D_ + co;
    float2 gi = *(const float2*)(g + base);
    float ax0 = gi.x, ay0 = gi.y, ax1 = 0.f, ay1 = 0.f;
    float ax2 = 0.f, ay2 = 0.f, ax3 = 0.f, ay3 = 0.f;
    int j = s0;
    for (; j + 8 <= s1; j += 8) {
        int i0 = csr[j], i1 = csr[j + 1], i2 = csr[j + 2], i3 = csr[j + 3];
        int i4 = csr[j + 4], i5 = csr[j + 5], i6 = csr[j + 6], i7 = csr[j + 7];
        float2 v0 = *(const float2*)(g + (size_t)i0 * D_ + co);
        float2 v1 = *(const float2*)(g + (size_t)i1 * D_ + co);
        float2 v2 = *(const float2*)(g + (size_t)i2 * D_ + co);
        float2 v3 = *(const float2*)(g + (size_t)i3 * D_ + co);
        float2 v4 = *(const float2*)(g + (size_t)i4 * D_ + co);
        float2 v5 = *(const float2*)(g + (size_t)i5 * D_ + co);
        float2 v6 = *(const float2*)(g + (size_t)i6 * D_ + co);
        float2 v7 = *(const float2*)(g + (size_t)i7 * D_ + co);
        ax0 += v0.x; ay0 += v0.y; ax1 += v1.x; ay1 += v1.y;
        ax2 += v2.x; ay2 += v2.y; ax3 += v3.x; ay3 += v3.y;
        ax0 += v4.x; ay0 += v4.y; ax1 += v5.x; ay1 += v5.y;
        ax2 += v6.x; ay2 += v6.y; ax3 += v7.x; ay3 += v7.y;
    }
    for (; j < s1; j++) {
        int s = csr[j];
        float2 gv = *(const float2*)(g + (size_t)s * D_ + co);
        ax0 += gv.x; ay0 += gv.y;
    }
    float ax = (ax0 + ax1) + (ax2 + ax3);
    float ay = (ay0 + ay1) + (ay2 + ay3);
    float2 b = *(const float2*)(bias + co);
    float2 o = make_float2(fmaxf(fmaf(ax, di, b.x), 0.f), fmaxf(fmaf(ay, di, b.y), 0.f));
    *(float2*)(out + base) = o;
    if (out2 && gw < BATCH_) *(float2*)(out2 + base) = o;
}

// ---------------- semantic attention partial scores for ONE type ----------------
// per row r of z (n rows): s_r = sum_a q[a]*tanh((z_r @ W_sem)[a] + b_sem[a])
__global__ __launch_bounds__(256) void k_att(const float* __restrict__ z,
                                             const float* __restrict__ Wsem,
                                             const float* __restrict__ bsem,
                                             const float* __restrict__ q,
                                             float* __restrict__ att_part, int n, int ttype) {
    __shared__ float Xs[64][136];
    __shared__ float Ws[64][64];
    __shared__ float sblk;
    int bid = blockIdx.x;
    int rt = bid >> 1, cb = bid & 1;
    int row0 = rt << 6;
    int t = threadIdx.x;
    if (t == 0) sblk = 0.f;
#pragma unroll
    for (int i = 0; i < 8; i++) {
        int f4 = t + (i << 8);
        int r = f4 >> 5, c4 = (f4 & 31) << 2;
        int gr = row0 + r;
        float4 v = make_float4(0.f, 0.f, 0.f, 0.f);
        if (gr < n) v = *(const float4*)(z + (size_t)gr * D_ + c4);
        *(float4*)&Xs[r][c4] = v;
    }
    int r0 = (t >> 4) << 2;
    int c0 = (t & 15) << 2;
    float acc[4][4] = {};
#pragma unroll
    for (int half = 0; half < 2; half++) {
        __syncthreads();
#pragma unroll
        for (int i = 0; i < 4; i++) {
            int f4 = t + (i << 8);
            int k = f4 >> 4, c4 = (f4 & 15) << 2;
            *(float4*)&Ws[k][c4] = *(const float4*)(Wsem + (size_t)((half << 6) + k) * D_ + (cb << 6) + c4);
        }
        __syncthreads();
#pragma unroll 4
        for (int k0 = 0; k0 < 64; k0 += 4) {
            float a_[4][4], b_[4][4];
#pragma unroll
            for (int rr = 0; rr < 4; rr++) {
                float4 v = *(float4*)&Xs[r0 + rr][(half << 6) + k0];
                a_[rr][0] = v.x; a_[rr][1] = v.y; a_[rr][2] = v.z; a_[rr][3] = v.w;
            }
#pragma unroll
            for (int kk = 0; kk < 4; kk++) {
                float4 v = *(float4*)&Ws[k0 + kk][c0];
                b_[kk][0] = v.x; b_[kk][1] = v.y; b_[kk][2] = v.z; b_[kk][3] = v.w;
            }
#pragma unroll
            for (int kk = 0; kk < 4; kk++)
#pragma unroll
                for (int rr = 0; rr < 4; rr++)
#pragma unroll
                    for (int cc = 0; cc < 4; cc++)
                        acc[rr][cc] = fmaf(a_[rr][kk], b_[kk][cc], acc[rr][cc]);
        }
    }
    int gcb = (cb << 6) + c0;
    float q0 = q[gcb], q1 = q[gcb + 1], q2 = q[gcb + 2], q3 = q[gcb + 3];
    float e0 = bsem[gcb], e1 = bsem[gcb + 1], e2 = bsem[gcb + 2], e3 = bsem[gcb + 3];
    int tc = t & 15;
    float s_[4];
#pragma unroll
    for (int rr = 0; rr < 4; rr++) {
        float s = q0 * tanhf(acc[rr][0] + e0) + q1 * tanhf(acc[rr][1] + e1) +
                  q2 * tanhf(acc[rr][2] + e2) + q3 * tanhf(acc[rr][3] + e3);
#pragma unroll
        for (int m = 1; m < 16; m <<= 1) s += __shfl_xor(s, m, 64);
        s_[rr] = s;
    }
    if (tc == 0) {
#pragma unroll
        for (int rr = 0; rr < 4; rr++) {
            if (row0 + r0 + rr < n) atomicAdd(&sblk, s_[rr]);
        }
    }
    __syncthreads();
    if (t == 0) atomicAdd(&att_part[((bid & 63) << 2) + ttype], sblk);
}

__global__ void k_attw(const float* __restrict__ att_part, float* __restrict__ att_w, float invN) {
    __shared__ float sb[3];
    int t = threadIdx.x;
    if (t < 3) {
        float s = 0.f;
        for (int i = 0; i < 64; i++) s += att_part[(i << 2) + t];
        sb[t] = s * invN;
    }
    __syncthreads();
    if (t == 0) {
        float m = fmaxf(sb[0], fmaxf(sb[1], sb[2]));
        float x0 = expf(sb[0] - m), x1 = expf(sb[1] - m), x2 = expf(sb[2] - m);
        float inv = 1.f / (x0 + x1 + x2);
        att_w[0] = x0 * inv; att_w[1] = x1 * inv; att_w[2] = x2 * inv;
    }
}

// ---------------- pos: column sums of combined rows (no materialization) ----------------
__global__ __launch_bounds__(256) void k_colsum(const float* __restrict__ Zb, size_t BD,
                                                const float* __restrict__ att_w,
                                                float* __restrict__ colsum) {
    int c2 = threadIdx.x & 63;
    int rg = threadIdx.x >> 6;
    int nbase = blockIdx.x << 7;  // 128 rows per block, 512 blocks = 65536 rows
    float w0 = att_w[0], w1 = att_w[1], w2 = att_w[2];
    float csx = 0.f, csy = 0.f;
    for (int i = rg; i < 128; i += 4) {
        size_t off = (size_t)(nbase + i) * D_ + (c2 << 1);
        float2 z0 = *(const float2*)(Zb + off);
        float2 z1 = *(const float2*)(Zb + BD + off);
        float2 z2 = *(const float2*)(Zb + 2 * BD + off);
        csx += w0 * z0.x + w1 * z1.x + w2 * z2.x;
        csy += w0 * z0.y + w1 * z1.y + w2 * z2.y;
    }
    __shared__ float red[4][128];
    red[rg][c2 << 1] = csx;
    red[rg][(c2 << 1) + 1] = csy;
    __syncthreads();
    if (rg == 0) {
        float sx = red[0][c2 << 1] + red[1][c2 << 1] + red[2][c2 << 1] + red[3][c2 << 1];
        float sy = red[0][(c2 << 1) + 1] + red[1][(c2 << 1) + 1] + red[2][(c2 << 1) + 1] + red[3][(c2 << 1) + 1];
        atomicAdd(&colsum[c2 << 1], sx);
        atomicAdd(&colsum[(c2 << 1) + 1], sy);
    }
}

__global__ void k_summary_c(const float* __restrict__ colsum, const float* __restrict__ sv,
                            const float* __restrict__ Wd, float* __restrict__ cvec,
                            float* __restrict__ out_summary) {
    __shared__ float sl[128];
    int t = threadIdx.x;  // 128 threads
    float s = 0.5f * (sv[t] + colsum[t] * (1.0f / (float)BATCH_));
    sl[t] = s;
    out_summary[t] = s;
    __syncthreads();
    float a = 0.f;
    for (int j = 0; j < 128; j++) a = fmaf(Wd[t * D_ + j], sl[j], a);
    cvec[t] = a;
}

// ---------------- score: combine z_t[:B] rows on the fly, dot with c ----------------
__global__ __launch_bounds__(256) void k_cscore(const float* __restrict__ Zb, size_t BD,
                                                const float* __restrict__ att_w,
                                                const float* __restrict__ c,
                                                const float* __restrict__ bd,
                                                float* __restrict__ out, int B) {
    int gw = (int)((blockIdx.x * (long long)blockDim.x + threadIdx.x) >> 6);
    int lane = threadIdx.x & 63;
    if (gw >= B) return;
    size_t off = (size_t)gw * D_ + (lane << 1);
    float w0 = att_w[0], w1 = att_w[1], w2 = att_w[2];
    float2 z0 = *(const float2*)(Zb + off);
    float2 z1 = *(const float2*)(Zb + BD + off);
    float2 z2 = *(const float2*)(Zb + 2 * BD + off);
    float vx = w0 * z0.x + w1 * z1.x + w2 * z2.x;
    float vy = w0 * z0.y + w1 * z1.y + w2 * z2.y;
    float2 cc = *(const float2*)(c + (lane << 1));
    float a = vx * cc.x + vy * cc.y;
#pragma unroll
    for (int m = 1; m < 64; m <<= 1) a += __shfl_xor(a, m, 64);
    if (lane == 0) out[gw] = a + bd[0];
}

// ---------------- host launcher ----------------
extern "C" void kernel_launch(void* const* d_in, const int* in_sizes, int n_in,
                              void* d_out, int out_size, void* d_ws, size_t ws_size,
                              hipStream_t stream) {
    const float* x      = (const float*)d_in[0];
    const int*   ei     = (const int*)d_in[1];    // int32 on device
    const int*   perm   = (const int*)d_in[2];    // int32 on device
    const float* sv     = (const float*)d_in[3];
    const float* W_lin  = (const float*)d_in[5];
    const float* b_lin  = (const float*)d_in[6];
    const float* W1     = (const float*)d_in[7];
    const float* b1     = (const float*)d_in[8];
    const float* W2     = (const float*)d_in[9];
    const float* b2     = (const float*)d_in[10];
    const float* W_sem  = (const float*)d_in[11];
    const float* b_sem  = (const float*)d_in[12];
    const float* q_sem  = (const float*)d_in[13];
    const float* W_disc = (const float*)d_in[14];
    const float* b_disc = (const float*)d_in[15];
    float* out = (float*)d_out;

    int N = in_sizes[0] / D_;
    int E = in_sizes[1] / 6;
    int L = 3 * N;
    size_t ND = (size_t)N * D_;
    size_t BD = (size_t)BATCH_ * D_;
    int B = BATCH_;

    char* ws = (char*)d_ws;
    size_t o = 0;
    auto alloc = [&](size_t bytes) -> char* {
        char* p = ws + o;
        o = (o + bytes + 255) & ~(size_t)255;
        return p;
    };
    // common small buffers first
    float* dinv     = (float*)alloc((size_t)L * 4);
    int*   cnt      = (int*)alloc((size_t)L * 4);
    int*   rowstart = (int*)alloc(((size_t)L + 1) * 4);
    int*   csr      = (int*)alloc((size_t)3 * E * 4);
    int*   bsum     = (int*)alloc(1024 * 4);
    int*   bscan    = (int*)alloc(1024 * 4);
    float* att_part = (float*)alloc(256 * 4);
    float* att_w    = (float*)alloc(16 * 4);   // [0..2]=pos, [8..10]=neg
    float* colsum   = (float*)alloc(128 * 4);
    float* cvec     = (float*)alloc(128 * 4);
    float* Zb       = (float*)alloc(3 * BD * 4);   // z_t[:B] per type
    size_t o_small = o;
    // full mode: A + G + H ; lean mode: G + H only (recompute x0 per type)
    float* G = (float*)alloc(ND * 4);
    float* H = (float*)alloc(ND * 4);
    size_t o_lean = o;
    float* A = (float*)alloc(ND * 4);
    size_t o_full = o;

    int mode;  // 0=full, 1=lean, 2=sentinel
    if (o_full <= ws_size) mode = 0;
    else if (o_lean <= ws_size) mode = 1;
    else mode = 2;
    if (mode == 2) {
        k_sentinel<<<256, 256, 0, stream>>>(out, out_size);
        return;
    }
    (void)o_small;

    // ---- CSR build (by destination), per edge type ----
    k_zero32<<<256, 256, 0, stream>>>((uint32_t*)cnt, L);
    k_count<<<2048, 256, 0, stream>>>(ei, cnt, N, E);
    k_dinv<<<(L + 255) / 256, 256, 0, stream>>>(cnt, dinv, L);
    int nb = (L + 511) / 512;
    k_scan1<<<nb, 512, 0, stream>>>(cnt, rowstart, bsum, L);
    k_scan2<<<1, 1024, 0, stream>>>(bsum, bscan, nb);
    k_scan3<<<(L + 255) / 256, 256, 0, stream>>>(rowstart, bscan, L, 3 * E);
    k_zero32<<<256, 256, 0, stream>>>((uint32_t*)cnt, L);
    k_fill<<<2048, 256, 0, stream>>>(ei, rowstart, cnt, csr, N, E);

    int gemm_grid = ((N + 63) / 64) * 2;
    int spmm_grid = (N + 3) / 4;
    int scoreB_grid = (B + 3) / 4;

    for (int br = 0; br < 2; br++) {
        const int* gidx = br ? perm : nullptr;
        float* aw = att_w + br * 8;
        if (mode == 0) {
            // x0 = relu( gather(x) @ W_lin + b_lin ), kept for all 3 types
            k_gemm<<<gemm_grid, 256, 0, stream>>>(x, gidx, W_lin, b_lin, nullptr, A, N, 1);
        }
        k_zero32<<<1, 256, 0, stream>>>((uint32_t*)att_part, 256);
        for (int t3 = 0; t3 < 3; t3++) {
            const int* rs = rowstart + (size_t)t3 * N;
            const float* dv = dinv + (size_t)t3 * N;
            float* Zbt = Zb + (size_t)t3 * BD;
            if (mode == 0) {
                k_gemm<<<gemm_grid, 256, 0, stream>>>(A, nullptr, W1, nullptr, dv, G, N, 0);
                k_spmm<<<spmm_grid, 256, 0, stream>>>(G, csr, rs, dv, b1, H, nullptr, N);   // h1
                k_gemm<<<gemm_grid, 256, 0, stream>>>(H, nullptr, W2, nullptr, dv, G, N, 0);
                k_spmm<<<spmm_grid, 256, 0, stream>>>(G, csr, rs, dv, b2, H, Zbt, N);       // z_t
                k_att<<<gemm_grid, 256, 0, stream>>>(H, W_sem, b_sem, q_sem, att_part, N, t3);
            } else {
                k_gemm<<<gemm_grid, 256, 0, stream>>>(x, gidx, W_lin, b_lin, nullptr, G, N, 1); // x0
                k_gemm<<<gemm_grid, 256, 0, stream>>>(G, nullptr, W1, nullptr, dv, H, N, 0);
                k_spmm<<<spmm_grid, 256, 0, stream>>>(H, csr, rs, dv, b1, G, nullptr, N);   // h1
                k_gemm<<<gemm_grid, 256, 0, stream>>>(G, nullptr, W2, nullptr, dv, H, N, 0);
                k_spmm<<<spmm_grid, 256, 0, stream>>>(H, csr, rs, dv, b2, G, Zbt, N);       // z_t
                k_att<<<gemm_grid, 256, 0, stream>>>(G, W_sem, b_sem, q_sem, att_part, N, t3);
            }
        }
        k_attw<<<1, 64, 0, stream>>>(att_part, aw, 1.0f / (float)N);
        if (br == 0) {
            k_zero32<<<1, 256, 0, stream>>>((uint32_t*)colsum, 128);
            k_colsum<<<512, 256, 0, stream>>>(Zb, BD, aw, colsum);
            k_summary_c<<<1, 128, 0, stream>>>(colsum, sv, W_disc, cvec, out + 2 * (size_t)B);
            k_cscore<<<scoreB_grid, 256, 0, stream>>>(Zb, BD, aw, cvec, b_disc, out, B);
        } else {
            k_cscore<<<scoreB_grid, 256, 0, stream>>>(Zb, BD, aw, cvec, b_disc, out + B, B);
        }
    }
}

// Round 4
// 2396.449 us; speedup vs baseline: 1.6680x; 1.4274x over previous
//
#include <hip/hip_runtime.h>

#define D_ 128
#define BATCH_ 65536

typedef _Float16 f16;
typedef _Float16 h2v __attribute__((ext_vector_type(2)));
typedef _Float16 h4v __attribute__((ext_vector_type(4)));

// ---------------- utility ----------------
__global__ void k_zero32(uint32_t* p, long long n) {
    long long i = (long long)blockIdx.x * blockDim.x + threadIdx.x;
    long long st = (long long)gridDim.x * blockDim.x;
    for (; i < n; i += st) p[i] = 0u;
}

__global__ void k_sentinel(float* p, long long n) {
    long long i = (long long)blockIdx.x * blockDim.x + threadIdx.x;
    long long st = (long long)gridDim.x * blockDim.x;
    for (; i < n; i += st) p[i] = -12345.0f;
}

// ---------------- CSR build (edge_index is int32 on device) ----------------
__global__ void k_count(const int* __restrict__ ei, int* __restrict__ cnt, int N, int E) {
    long long i = (long long)blockIdx.x * blockDim.x + threadIdx.x;
    long long st = (long long)gridDim.x * blockDim.x;
    long long tot = 3LL * E;
    for (; i < tot; i += st) {
        int t = (int)(i / E);
        int w = (int)(i - (long long)t * E);
        int dst = ei[(long long)t * 2 * E + E + w];
        atomicAdd(&cnt[t * N + dst], 1);
    }
}

__global__ void k_dinv(const int* __restrict__ cnt, float* __restrict__ dinv, int L) {
    int i = blockIdx.x * blockDim.x + threadIdx.x;
    if (i < L) dinv[i] = rsqrtf((float)cnt[i] + 1.0f);
}

__global__ void k_scan1(const int* __restrict__ in, int* __restrict__ excl,
                        int* __restrict__ bsum, int L) {
    __shared__ int s[512];
    int t = threadIdx.x;
    int g = blockIdx.x * 512 + t;
    int v = (g < L) ? in[g] : 0;
    s[t] = v;
    __syncthreads();
    for (int off = 1; off < 512; off <<= 1) {
        int a = (t >= off) ? s[t - off] : 0;
        __syncthreads();
        s[t] += a;
        __syncthreads();
    }
    if (g < L) excl[g] = s[t] - v;
    if (t == 511) bsum[blockIdx.x] = s[511];
}

__global__ void k_scan2(const int* __restrict__ bsum, int* __restrict__ bscan, int nb) {
    __shared__ int s[1024];
    int t = threadIdx.x;
    int v = (t < nb) ? bsum[t] : 0;
    s[t] = v;
    __syncthreads();
    for (int off = 1; off < 1024; off <<= 1) {
        int a = (t >= off) ? s[t - off] : 0;
        __syncthreads();
        s[t] += a;
        __syncthreads();
    }
    bscan[t] = s[t] - v;  // exclusive
}

__global__ void k_scan3(int* __restrict__ excl, const int* __restrict__ bscan, int L, int total) {
    int g = blockIdx.x * blockDim.x + threadIdx.x;
    if (g < L) excl[g] += bscan[g >> 9];
    if (g == 0) excl[L] = total;
}

__global__ void k_fill(const int* __restrict__ ei, const int* __restrict__ rowstart,
                       int* __restrict__ cur, int* __restrict__ csr, int N, int E) {
    long long i = (long long)blockIdx.x * blockDim.x + threadIdx.x;
    long long st = (long long)gridDim.x * blockDim.x;
    long long tot = 3LL * E;
    for (; i < tot; i += st) {
        int t = (int)(i / E);
        int w = (int)(i - (long long)t * E);
        int src = ei[(long long)t * 2 * E + w];
        int dst = ei[(long long)t * 2 * E + E + w];
        int r = t * N + dst;
        int pos = rowstart[r] + atomicAdd(&cur[r], 1);
        csr[pos] = src;
    }
}

// ---------------- dense GEMM: out = [relu](in @ W [+ bias]) [* scale[row]], f32 or fp16 out ----
// 64x64 tile per block, 256 threads, 4x4 acc per thread, W staged in two 64-row halves.
__global__ __launch_bounds__(256) void k_gemm(const float* __restrict__ in,
                                              const float* __restrict__ W,
                                              const float* __restrict__ bias,
                                              const float* __restrict__ scale,
                                              float* __restrict__ outf,
                                              f16* __restrict__ outh,
                                              int n, int relu) {
    __shared__ float Xs[64][136];
    __shared__ float Ws[64][64];
    int bid = blockIdx.x;
    int rt = bid >> 1, cb = bid & 1;
    int row0 = rt << 6;
    int t = threadIdx.x;
#pragma unroll
    for (int i = 0; i < 8; i++) {
        int f4 = t + (i << 8);
        int r = f4 >> 5, c4 = (f4 & 31) << 2;
        int gr = row0 + r;
        float4 v = make_float4(0.f, 0.f, 0.f, 0.f);
        if (gr < n) v = *(const float4*)(in + (size_t)gr * D_ + c4);
        *(float4*)&Xs[r][c4] = v;
    }
    int r0 = (t >> 4) << 2;
    int c0 = (t & 15) << 2;
    float acc[4][4] = {};
#pragma unroll
    for (int half = 0; half < 2; half++) {
        __syncthreads();
#pragma unroll
        for (int i = 0; i < 4; i++) {
            int f4 = t + (i << 8);
            int k = f4 >> 4, c4 = (f4 & 15) << 2;
            *(float4*)&Ws[k][c4] = *(const float4*)(W + (size_t)((half << 6) + k) * D_ + (cb << 6) + c4);
        }
        __syncthreads();
#pragma unroll 4
        for (int k0 = 0; k0 < 64; k0 += 4) {
            float a_[4][4], b_[4][4];
#pragma unroll
            for (int rr = 0; rr < 4; rr++) {
                float4 v = *(float4*)&Xs[r0 + rr][(half << 6) + k0];
                a_[rr][0] = v.x; a_[rr][1] = v.y; a_[rr][2] = v.z; a_[rr][3] = v.w;
            }
#pragma unroll
            for (int kk = 0; kk < 4; kk++) {
                float4 v = *(float4*)&Ws[k0 + kk][c0];
                b_[kk][0] = v.x; b_[kk][1] = v.y; b_[kk][2] = v.z; b_[kk][3] = v.w;
            }
#pragma unroll
            for (int kk = 0; kk < 4; kk++)
#pragma unroll
                for (int rr = 0; rr < 4; rr++)
#pragma unroll
                    for (int cc = 0; cc < 4; cc++)
                        acc[rr][cc] = fmaf(a_[rr][kk], b_[kk][cc], acc[rr][cc]);
        }
    }
    int gcb = (cb << 6) + c0;
#pragma unroll
    for (int rr = 0; rr < 4; rr++) {
        int gr = row0 + r0 + rr;
        if (gr >= n) continue;
        float4 o;
        o.x = acc[rr][0]; o.y = acc[rr][1]; o.z = acc[rr][2]; o.w = acc[rr][3];
        if (bias) { o.x += bias[gcb]; o.y += bias[gcb + 1]; o.z += bias[gcb + 2]; o.w += bias[gcb + 3]; }
        if (relu) {
            o.x = fmaxf(o.x, 0.f); o.y = fmaxf(o.y, 0.f);
            o.z = fmaxf(o.z, 0.f); o.w = fmaxf(o.w, 0.f);
        }
        if (scale) {
            float sc = scale[gr];
            o.x *= sc; o.y *= sc; o.z *= sc; o.w *= sc;
        }
        if (outf) {
            *(float4*)(outf + (size_t)gr * D_ + gcb) = o;
        } else {
            h4v h;
            h.x = (f16)o.x; h.y = (f16)o.y; h.z = (f16)o.z; h.w = (f16)o.w;
            *(h4v*)(outh + (size_t)gr * D_ + gcb) = h;
        }
    }
}

// ---------------- GCN aggregate (gather CSR over fp16 rows) ----------------
// edge_dinv=1 (layer1): out[i] = relu((Σ_j g[pi(src_j)]*dinv[src_j] + g[pi(i)]*dinv[i])*dinv[i]+b)
// edge_dinv=0 (layer2): g pre-scaled by dinv:  out[i] = relu((Σ_j g[src_j] + g[i])*dinv[i]+b)
// unrolled x8 for memory-level parallelism (gathers are L2/L3-resident, latency-bound).
__global__ __launch_bounds__(256) void k_spmm(const f16* __restrict__ g,
                                              const int* __restrict__ csr,
                                              const int* __restrict__ rowstart,
                                              const float* __restrict__ dinv,
                                              const int* __restrict__ permp,
                                              const float* __restrict__ bias,
                                              float* __restrict__ out,
                                              f16* __restrict__ out2,
                                              int n, int edge_dinv) {
    int gw = (int)((blockIdx.x * (long long)blockDim.x + threadIdx.x) >> 6);
    int lane = threadIdx.x & 63;
    if (gw >= n) return;
    int s0 = rowstart[gw], s1 = rowstart[gw + 1];
    float di = dinv[gw];
    size_t co = (size_t)(lane << 1);
    int self = permp ? permp[gw] : gw;
    h2v gi = *(const h2v*)(g + (size_t)self * D_ + co);
    float wself = edge_dinv ? di : 1.0f;
    float ax0 = (float)gi.x * wself, ay0 = (float)gi.y * wself;
    float ax1 = 0.f, ay1 = 0.f, ax2 = 0.f, ay2 = 0.f, ax3 = 0.f, ay3 = 0.f;
    int j = s0;
    if (edge_dinv) {
        for (; j + 8 <= s1; j += 8) {
            int s[8];
#pragma unroll
            for (int u = 0; u < 8; u++) s[u] = csr[j + u];
            float w[8];
            int r[8];
#pragma unroll
            for (int u = 0; u < 8; u++) { w[u] = dinv[s[u]]; r[u] = permp ? permp[s[u]] : s[u]; }
            h2v v[8];
#pragma unroll
            for (int u = 0; u < 8; u++) v[u] = *(const h2v*)(g + (size_t)r[u] * D_ + co);
            ax0 = fmaf((float)v[0].x, w[0], ax0); ay0 = fmaf((float)v[0].y, w[0], ay0);
            ax1 = fmaf((float)v[1].x, w[1], ax1); ay1 = fmaf((float)v[1].y, w[1], ay1);
            ax2 = fmaf((float)v[2].x, w[2], ax2); ay2 = fmaf((float)v[2].y, w[2], ay2);
            ax3 = fmaf((float)v[3].x, w[3], ax3); ay3 = fmaf((float)v[3].y, w[3], ay3);
            ax0 = fmaf((float)v[4].x, w[4], ax0); ay0 = fmaf((float)v[4].y, w[4], ay0);
            ax1 = fmaf((float)v[5].x, w[5], ax1); ay1 = fmaf((float)v[5].y, w[5], ay1);
            ax2 = fmaf((float)v[6].x, w[6], ax2); ay2 = fmaf((float)v[6].y, w[6], ay2);
            ax3 = fmaf((float)v[7].x, w[7], ax3); ay3 = fmaf((float)v[7].y, w[7], ay3);
        }
        for (; j < s1; j++) {
            int s = csr[j];
            float w = dinv[s];
            int r = permp ? permp[s] : s;
            h2v v = *(const h2v*)(g + (size_t)r * D_ + co);
            ax0 = fmaf((float)v.x, w, ax0); ay0 = fmaf((float)v.y, w, ay0);
        }
    } else {
        for (; j + 8 <= s1; j += 8) {
            int s[8];
#pragma unroll
            for (int u = 0; u < 8; u++) s[u] = csr[j + u];
            h2v v[8];
#pragma unroll
            for (int u = 0; u < 8; u++) v[u] = *(const h2v*)(g + (size_t)s[u] * D_ + co);
            ax0 += (float)v[0].x; ay0 += (float)v[0].y;
            ax1 += (float)v[1].x; ay1 += (float)v[1].y;
            ax2 += (float)v[2].x; ay2 += (float)v[2].y;
            ax3 += (float)v[3].x; ay3 += (float)v[3].y;
            ax0 += (float)v[4].x; ay0 += (float)v[4].y;
            ax1 += (float)v[5].x; ay1 += (float)v[5].y;
            ax2 += (float)v[6].x; ay2 += (float)v[6].y;
            ax3 += (float)v[7].x; ay3 += (float)v[7].y;
        }
        for (; j < s1; j++) {
            int s = csr[j];
            h2v v = *(const h2v*)(g + (size_t)s * D_ + co);
            ax0 += (float)v.x; ay0 += (float)v.y;
        }
    }
    float ax = (ax0 + ax1) + (ax2 + ax3);
    float ay = (ay0 + ay1) + (ay2 + ay3);
    size_t base = (size_t)gw * D_ + co;
    float2 b = *(const float2*)(bias + co);
    float ox = fmaxf(fmaf(ax, di, b.x), 0.f);
    float oy = fmaxf(fmaf(ay, di, b.y), 0.f);
    *(float2*)(out + base) = make_float2(ox, oy);
    if (out2 && gw < BATCH_) {
        h2v h;
        h.x = (f16)ox; h.y = (f16)oy;
        *(h2v*)(out2 + base) = h;
    }
}

// ---------------- semantic attention partial scores for ONE type ----------------
__global__ __launch_bounds__(256) void k_att(const float* __restrict__ z,
                                             const float* __restrict__ Wsem,
                                             const float* __restrict__ bsem,
                                             const float* __restrict__ q,
                                             float* __restrict__ att_part, int n, int ttype) {
    __shared__ float Xs[64][136];
    __shared__ float Ws[64][64];
    __shared__ float sblk;
    int bid = blockIdx.x;
    int rt = bid >> 1, cb = bid & 1;
    int row0 = rt << 6;
    int t = threadIdx.x;
    if (t == 0) sblk = 0.f;
#pragma unroll
    for (int i = 0; i < 8; i++) {
        int f4 = t + (i << 8);
        int r = f4 >> 5, c4 = (f4 & 31) << 2;
        int gr = row0 + r;
        float4 v = make_float4(0.f, 0.f, 0.f, 0.f);
        if (gr < n) v = *(const float4*)(z + (size_t)gr * D_ + c4);
        *(float4*)&Xs[r][c4] = v;
    }
    int r0 = (t >> 4) << 2;
    int c0 = (t & 15) << 2;
    float acc[4][4] = {};
#pragma unroll
    for (int half = 0; half < 2; half++) {
        __syncthreads();
#pragma unroll
        for (int i = 0; i < 4; i++) {
            int f4 = t + (i << 8);
            int k = f4 >> 4, c4 = (f4 & 15) << 2;
            *(float4*)&Ws[k][c4] = *(const float4*)(Wsem + (size_t)((half << 6) + k) * D_ + (cb << 6) + c4);
        }
        __syncthreads();
#pragma unroll 4
        for (int k0 = 0; k0 < 64; k0 += 4) {
            float a_[4][4], b_[4][4];
#pragma unroll
            for (int rr = 0; rr < 4; rr++) {
                float4 v = *(float4*)&Xs[r0 + rr][(half << 6) + k0];
                a_[rr][0] = v.x; a_[rr][1] = v.y; a_[rr][2] = v.z; a_[rr][3] = v.w;
            }
#pragma unroll
            for (int kk = 0; kk < 4; kk++) {
                float4 v = *(float4*)&Ws[k0 + kk][c0];
                b_[kk][0] = v.x; b_[kk][1] = v.y; b_[kk][2] = v.z; b_[kk][3] = v.w;
            }
#pragma unroll
            for (int kk = 0; kk < 4; kk++)
#pragma unroll
                for (int rr = 0; rr < 4; rr++)
#pragma unroll
                    for (int cc = 0; cc < 4; cc++)
                        acc[rr][cc] = fmaf(a_[rr][kk], b_[kk][cc], acc[rr][cc]);
        }
    }
    int gcb = (cb << 6) + c0;
    float q0 = q[gcb], q1 = q[gcb + 1], q2 = q[gcb + 2], q3 = q[gcb + 3];
    float e0 = bsem[gcb], e1 = bsem[gcb + 1], e2 = bsem[gcb + 2], e3 = bsem[gcb + 3];
    int tc = t & 15;
    float s_[4];
#pragma unroll
    for (int rr = 0; rr < 4; rr++) {
        float s = q0 * tanhf(acc[rr][0] + e0) + q1 * tanhf(acc[rr][1] + e1) +
                  q2 * tanhf(acc[rr][2] + e2) + q3 * tanhf(acc[rr][3] + e3);
#pragma unroll
        for (int m = 1; m < 16; m <<= 1) s += __shfl_xor(s, m, 64);
        s_[rr] = s;
    }
    if (tc == 0) {
#pragma unroll
        for (int rr = 0; rr < 4; rr++) {
            if (row0 + r0 + rr < n) atomicAdd(&sblk, s_[rr]);
        }
    }
    __syncthreads();
    if (t == 0) atomicAdd(&att_part[((bid & 63) << 2) + ttype], sblk);
}

__global__ void k_attw(const float* __restrict__ att_part, float* __restrict__ att_w, float invN) {
    __shared__ float sb[3];
    int t = threadIdx.x;
    if (t < 3) {
        float s = 0.f;
        for (int i = 0; i < 64; i++) s += att_part[(i << 2) + t];
        sb[t] = s * invN;
    }
    __syncthreads();
    if (t == 0) {
        float m = fmaxf(sb[0], fmaxf(sb[1], sb[2]));
        float x0 = expf(sb[0] - m), x1 = expf(sb[1] - m), x2 = expf(sb[2] - m);
        float inv = 1.f / (x0 + x1 + x2);
        att_w[0] = x0 * inv; att_w[1] = x1 * inv; att_w[2] = x2 * inv;
    }
}

// ---------------- pos: column sums of combined rows (Zb fp16) ----------------
__global__ __launch_bounds__(256) void k_colsum(const f16* __restrict__ Zb, size_t BD,
                                                const float* __restrict__ att_w,
                                                float* __restrict__ colsum) {
    int c2 = threadIdx.x & 63;
    int rg = threadIdx.x >> 6;
    int nbase = blockIdx.x << 7;  // 128 rows per block, 512 blocks = 65536 rows
    float w0 = att_w[0], w1 = att_w[1], w2 = att_w[2];
    float csx = 0.f, csy = 0.f;
    for (int i = rg; i < 128; i += 4) {
        size_t off = (size_t)(nbase + i) * D_ + (c2 << 1);
        h2v z0 = *(const h2v*)(Zb + off);
        h2v z1 = *(const h2v*)(Zb + BD + off);
        h2v z2 = *(const h2v*)(Zb + 2 * BD + off);
        csx += w0 * (float)z0.x + w1 * (float)z1.x + w2 * (float)z2.x;
        csy += w0 * (float)z0.y + w1 * (float)z1.y + w2 * (float)z2.y;
    }
    __shared__ float red[4][128];
    red[rg][c2 << 1] = csx;
    red[rg][(c2 << 1) + 1] = csy;
    __syncthreads();
    if (rg == 0) {
        float sx = red[0][c2 << 1] + red[1][c2 << 1] + red[2][c2 << 1] + red[3][c2 << 1];
        float sy = red[0][(c2 << 1) + 1] + red[1][(c2 << 1) + 1] + red[2][(c2 << 1) + 1] + red[3][(c2 << 1) + 1];
        atomicAdd(&colsum[c2 << 1], sx);
        atomicAdd(&colsum[(c2 << 1) + 1], sy);
    }
}

__global__ void k_summary_c(const float* __restrict__ colsum, const float* __restrict__ sv,
                            const float* __restrict__ Wd, float* __restrict__ cvec,
                            float* __restrict__ out_summary) {
    __shared__ float sl[128];
    int t = threadIdx.x;  // 128 threads
    float s = 0.5f * (sv[t] + colsum[t] * (1.0f / (float)BATCH_));
    sl[t] = s;
    out_summary[t] = s;
    __syncthreads();
    float a = 0.f;
    for (int j = 0; j < 128; j++) a = fmaf(Wd[t * D_ + j], sl[j], a);
    cvec[t] = a;
}

// ---------------- score: combine z_t[:B] rows on the fly, dot with c ----------------
__global__ __launch_bounds__(256) void k_cscore(const f16* __restrict__ Zb, size_t BD,
                                                const float* __restrict__ att_w,
                                                const float* __restrict__ c,
                                                const float* __restrict__ bd,
                                                float* __restrict__ out, int B) {
    int gw = (int)((blockIdx.x * (long long)blockDim.x + threadIdx.x) >> 6);
    int lane = threadIdx.x & 63;
    if (gw >= B) return;
    size_t off = (size_t)gw * D_ + (lane << 1);
    float w0 = att_w[0], w1 = att_w[1], w2 = att_w[2];
    h2v z0 = *(const h2v*)(Zb + off);
    h2v z1 = *(const h2v*)(Zb + BD + off);
    h2v z2 = *(const h2v*)(Zb + 2 * BD + off);
    float vx = w0 * (float)z0.x + w1 * (float)z1.x + w2 * (float)z2.x;
    float vy = w0 * (float)z0.y + w1 * (float)z1.y + w2 * (float)z2.y;
    float2 cc = *(const float2*)(c + (lane << 1));
    float a = vx * cc.x + vy * cc.y;
#pragma unroll
    for (int m = 1; m < 64; m <<= 1) a += __shfl_xor(a, m, 64);
    if (lane == 0) out[gw] = a + bd[0];
}

// ---------------- host launcher ----------------
extern "C" void kernel_launch(void* const* d_in, const int* in_sizes, int n_in,
                              void* d_out, int out_size, void* d_ws, size_t ws_size,
                              hipStream_t stream) {
    const float* x      = (const float*)d_in[0];
    const int*   ei     = (const int*)d_in[1];    // int32 on device
    const int*   perm   = (const int*)d_in[2];    // int32 on device
    const float* sv     = (const float*)d_in[3];
    const float* W_lin  = (const float*)d_in[5];
    const float* b_lin  = (const float*)d_in[6];
    const float* W1     = (const float*)d_in[7];
    const float* b1     = (const float*)d_in[8];
    const float* W2     = (const float*)d_in[9];
    const float* b2     = (const float*)d_in[10];
    const float* W_sem  = (const float*)d_in[11];
    const float* b_sem  = (const float*)d_in[12];
    const float* q_sem  = (const float*)d_in[13];
    const float* W_disc = (const float*)d_in[14];
    const float* b_disc = (const float*)d_in[15];
    float* out = (float*)d_out;

    int N = in_sizes[0] / D_;
    int E = in_sizes[1] / 6;
    int L = 3 * N;
    size_t ND = (size_t)N * D_;
    size_t BD = (size_t)BATCH_ * D_;
    int B = BATCH_;

    char* ws = (char*)d_ws;
    size_t o = 0;
    auto alloc = [&](size_t bytes) -> char* {
        char* p = ws + o;
        o = (o + bytes + 255) & ~(size_t)255;
        return p;
    };
    float* dinv     = (float*)alloc((size_t)L * 4);
    int*   cnt      = (int*)alloc((size_t)L * 4);
    int*   rowstart = (int*)alloc(((size_t)L + 1) * 4);
    int*   csr      = (int*)alloc((size_t)3 * E * 4);
    int*   bsum     = (int*)alloc(1024 * 4);
    int*   bscan    = (int*)alloc(1024 * 4);
    float* att_part = (float*)alloc(256 * 4);
    float* att_w    = (float*)alloc(16 * 4);   // [0..2]=pos, [8..10]=neg
    float* colsum   = (float*)alloc(128 * 4);
    float* cvec     = (float*)alloc(128 * 4);
    f16*   Zb       = (f16*)alloc(3 * BD * 2);    // z_t[:B] per type, fp16
    float* A        = (float*)alloc(ND * 4);      // relu(x@Wlin+b)
    f16*   G1h      = (f16*)alloc(ND * 2);        // A@W1, unscaled fp16 (shared both branches)
    f16*   G2h      = (f16*)alloc(ND * 2);        // h1@W2 * dinv_t, fp16
    float* H        = (float*)alloc(ND * 4);      // h1 / z scratch f32
    size_t o_full = o;

    if (o_full > ws_size) {
        k_sentinel<<<256, 256, 0, stream>>>(out, out_size);
        return;
    }

    // ---- CSR build (by destination), per edge type ----
    k_zero32<<<256, 256, 0, stream>>>((uint32_t*)cnt, L);
    k_count<<<2048, 256, 0, stream>>>(ei, cnt, N, E);
    k_dinv<<<(L + 255) / 256, 256, 0, stream>>>(cnt, dinv, L);
    int nb = (L + 511) / 512;
    k_scan1<<<nb, 512, 0, stream>>>(cnt, rowstart, bsum, L);
    k_scan2<<<1, 1024, 0, stream>>>(bsum, bscan, nb);
    k_scan3<<<(L + 255) / 256, 256, 0, stream>>>(rowstart, bscan, L, 3 * E);
    k_zero32<<<256, 256, 0, stream>>>((uint32_t*)cnt, L);
    k_fill<<<2048, 256, 0, stream>>>(ei, rowstart, cnt, csr, N, E);

    int gemm_grid = ((N + 63) / 64) * 2;
    int spmm_grid = (N + 3) / 4;
    int scoreB_grid = (B + 3) / 4;

    // shared across branches: A = relu(x@Wlin+b);  G1 = A@W1 (fp16, unscaled)
    k_gemm<<<gemm_grid, 256, 0, stream>>>(x, W_lin, b_lin, nullptr, A, nullptr, N, 1);
    k_gemm<<<gemm_grid, 256, 0, stream>>>(A, W1, nullptr, nullptr, nullptr, G1h, N, 0);

    for (int br = 0; br < 2; br++) {
        const int* permp = br ? perm : nullptr;
        float* aw = att_w + br * 8;
        k_zero32<<<1, 256, 0, stream>>>((uint32_t*)att_part, 256);
        for (int t3 = 0; t3 < 3; t3++) {
            const int* rs = rowstart + (size_t)t3 * N;
            const float* dv = dinv + (size_t)t3 * N;
            f16* Zbt = Zb + (size_t)t3 * BD;
            // h1 = relu(agg_t(G1[perm]) * dinv + b1)
            k_spmm<<<spmm_grid, 256, 0, stream>>>(G1h, csr, rs, dv, permp, b1, H, nullptr, N, 1);
            // G2 = (h1 @ W2) * dinv, fp16
            k_gemm<<<gemm_grid, 256, 0, stream>>>(H, W2, nullptr, dv, nullptr, G2h, N, 0);
            // z_t = relu(agg_t(G2) * dinv + b2)  (pre-scaled)
            k_spmm<<<spmm_grid, 256, 0, stream>>>(G2h, csr, rs, dv, nullptr, b2, H, Zbt, N, 0);
            k_att<<<gemm_grid, 256, 0, stream>>>(H, W_sem, b_sem, q_sem, att_part, N, t3);
        }
        k_attw<<<1, 64, 0, stream>>>(att_part, aw, 1.0f / (float)N);
        if (br == 0) {
            k_zero32<<<1, 256, 0, stream>>>((uint32_t*)colsum, 128);
            k_colsum<<<512, 256, 0, stream>>>(Zb, BD, aw, colsum);
            k_summary_c<<<1, 128, 0, stream>>>(colsum, sv, W_disc, cvec, out + 2 * (size_t)B);
            k_cscore<<<scoreB_grid, 256, 0, stream>>>(Zb, BD, aw, cvec, b_disc, out, B);
        } else {
            k_cscore<<<scoreB_grid, 256, 0, stream>>>(Zb, BD, aw, cvec, b_disc, out + B, B);
        }
    }
}

// Round 5
// 2096.297 us; speedup vs baseline: 1.9068x; 1.1432x over previous
//
#include <hip/hip_runtime.h>

#define D_ 128
#define BATCH_ 65536

typedef _Float16 f16;
typedef _Float16 h2v __attribute__((ext_vector_type(2)));
typedef _Float16 f16x8 __attribute__((ext_vector_type(8)));
typedef float f32x4 __attribute__((ext_vector_type(4)));

// ---------------- utility ----------------
__global__ void k_zero32(uint32_t* p, long long n) {
    long long i = (long long)blockIdx.x * blockDim.x + threadIdx.x;
    long long st = (long long)gridDim.x * blockDim.x;
    for (; i < n; i += st) p[i] = 0u;
}

__global__ void k_sentinel(float* p, long long n) {
    long long i = (long long)blockIdx.x * blockDim.x + threadIdx.x;
    long long st = (long long)gridDim.x * blockDim.x;
    for (; i < n; i += st) p[i] = -12345.0f;
}

// transpose+convert 128x128 weight: Wt[c][k] = (f16)W[k][c]
__global__ void k_wt(const float* __restrict__ W, f16* __restrict__ Wt) {
    int t = blockIdx.x * 256 + threadIdx.x;  // grid 64 -> 16384
    int k = t >> 7, c = t & 127;
    Wt[c * 128 + k] = (f16)W[k * 128 + c];
}

// ---------------- CSR build (edge_index is int32 on device) ----------------
__global__ void k_count(const int* __restrict__ ei, int* __restrict__ cnt, int N, int E) {
    long long i = (long long)blockIdx.x * blockDim.x + threadIdx.x;
    long long st = (long long)gridDim.x * blockDim.x;
    long long tot = 3LL * E;
    for (; i < tot; i += st) {
        int t = (int)(i / E);
        int w = (int)(i - (long long)t * E);
        int dst = ei[(long long)t * 2 * E + E + w];
        atomicAdd(&cnt[t * N + dst], 1);
    }
}

__global__ void k_dinv(const int* __restrict__ cnt, float* __restrict__ dinv, int L) {
    int i = blockIdx.x * blockDim.x + threadIdx.x;
    if (i < L) dinv[i] = rsqrtf((float)cnt[i] + 1.0f);
}

__global__ void k_scan1(const int* __restrict__ in, int* __restrict__ excl,
                        int* __restrict__ bsum, int L) {
    __shared__ int s[512];
    int t = threadIdx.x;
    int g = blockIdx.x * 512 + t;
    int v = (g < L) ? in[g] : 0;
    s[t] = v;
    __syncthreads();
    for (int off = 1; off < 512; off <<= 1) {
        int a = (t >= off) ? s[t - off] : 0;
        __syncthreads();
        s[t] += a;
        __syncthreads();
    }
    if (g < L) excl[g] = s[t] - v;
    if (t == 511) bsum[blockIdx.x] = s[511];
}

__global__ void k_scan2(const int* __restrict__ bsum, int* __restrict__ bscan, int nb) {
    __shared__ int s[1024];
    int t = threadIdx.x;
    int v = (t < nb) ? bsum[t] : 0;
    s[t] = v;
    __syncthreads();
    for (int off = 1; off < 1024; off <<= 1) {
        int a = (t >= off) ? s[t - off] : 0;
        __syncthreads();
        s[t] += a;
        __syncthreads();
    }
    bscan[t] = s[t] - v;  // exclusive
}

__global__ void k_scan3(int* __restrict__ excl, const int* __restrict__ bscan, int L, int total) {
    int g = blockIdx.x * blockDim.x + threadIdx.x;
    if (g < L) excl[g] += bscan[g >> 9];
    if (g == 0) excl[L] = total;
}

__global__ void k_fill(const int* __restrict__ ei, const int* __restrict__ rowstart,
                       int* __restrict__ cur, int* __restrict__ csr, int N, int E) {
    long long i = (long long)blockIdx.x * blockDim.x + threadIdx.x;
    long long st = (long long)gridDim.x * blockDim.x;
    long long tot = 3LL * E;
    for (; i < tot; i += st) {
        int t = (int)(i / E);
        int w = (int)(i - (long long)t * E);
        int src = ei[(long long)t * 2 * E + w];
        int dst = ei[(long long)t * 2 * E + E + w];
        int r = t * N + dst;
        int pos = rowstart[r] + atomicAdd(&cur[r], 1);
        csr[pos] = src;
    }
}

// ---------------- MFMA GEMM: out(f16) = [relu](in @ W [+ bias]) [* scale[row]] ----------------
// in: row-major [n][128] f32 or f16; Wt: [c][k] f16 (transposed). Block=256 (4 waves),
// each wave does 16 rows x 128 cols, K=128 via 4x mfma_f32_16x16x32_f16 per col-tile.
__global__ __launch_bounds__(256) void k_mgemm(const void* __restrict__ in, int in_f32,
                                               const f16* __restrict__ Wt,
                                               const float* __restrict__ bias,
                                               const float* __restrict__ scale,
                                               f16* __restrict__ outh, int n, int relu) {
    int l = threadIdx.x & 63, wid = threadIdx.x >> 6;
    int row0 = blockIdx.x * 64 + wid * 16;
    int r = l & 15, kg = l >> 4;
    int arow = row0 + r;
    f32x4 acc[8] = {};
#pragma unroll
    for (int kk = 0; kk < 4; kk++) {
        int off = kk * 32 + kg * 8;
        f16x8 a = {};
        if (arow < n) {
            if (in_f32) {
                const float* inf = (const float*)in + (size_t)arow * D_ + off;
                float4 v0 = *(const float4*)inf;
                float4 v1 = *(const float4*)(inf + 4);
                a[0] = (f16)v0.x; a[1] = (f16)v0.y; a[2] = (f16)v0.z; a[3] = (f16)v0.w;
                a[4] = (f16)v1.x; a[5] = (f16)v1.y; a[6] = (f16)v1.z; a[7] = (f16)v1.w;
            } else {
                a = *(const f16x8*)((const f16*)in + (size_t)arow * D_ + off);
            }
        }
#pragma unroll
        for (int ct = 0; ct < 8; ct++) {
            int c = ct * 16 + r;
            f16x8 b = *(const f16x8*)(Wt + (size_t)c * D_ + off);
            acc[ct] = __builtin_amdgcn_mfma_f32_16x16x32_f16(a, b, acc[ct], 0, 0, 0);
        }
    }
    // epilogue: C/D layout row=(l>>4)*4+j, col=l&15
    float sc[4];
#pragma unroll
    for (int j = 0; j < 4; j++) {
        int rr = row0 + kg * 4 + j;
        sc[j] = (scale && rr < n) ? scale[rr] : 1.0f;
    }
#pragma unroll
    for (int ct = 0; ct < 8; ct++) {
        int c = ct * 16 + r;
        float bs = bias ? bias[c] : 0.0f;
#pragma unroll
        for (int j = 0; j < 4; j++) {
            int rr = row0 + kg * 4 + j;
            if (rr >= n) continue;
            float o = acc[ct][j] + bs;
            if (relu) o = fmaxf(o, 0.0f);
            o *= sc[j];
            outh[(size_t)rr * D_ + c] = (f16)o;
        }
    }
}

// ---------------- MFMA semantic attention: sum_r q . tanh(z_r @ Wsem + bsem) ----------------
__global__ __launch_bounds__(256) void k_matt(const f16* __restrict__ z,
                                              const f16* __restrict__ Wst,
                                              const float* __restrict__ bsem,
                                              const float* __restrict__ q,
                                              float* __restrict__ att_part, int n, int ttype) {
    int l = threadIdx.x & 63, wid = threadIdx.x >> 6;
    int row0 = blockIdx.x * 64 + wid * 16;
    int r = l & 15, kg = l >> 4;
    int arow = row0 + r;
    f32x4 acc[8] = {};
#pragma unroll
    for (int kk = 0; kk < 4; kk++) {
        int off = kk * 32 + kg * 8;
        f16x8 a = {};
        if (arow < n) a = *(const f16x8*)(z + (size_t)arow * D_ + off);
#pragma unroll
        for (int ct = 0; ct < 8; ct++) {
            int c = ct * 16 + r;
            f16x8 b = *(const f16x8*)(Wst + (size_t)c * D_ + off);
            acc[ct] = __builtin_amdgcn_mfma_f32_16x16x32_f16(a, b, acc[ct], 0, 0, 0);
        }
    }
    float s = 0.0f;
#pragma unroll
    for (int ct = 0; ct < 8; ct++) {
        int c = ct * 16 + r;
        float qc = q[c], bc = bsem[c];
#pragma unroll
        for (int j = 0; j < 4; j++) {
            int rr = row0 + kg * 4 + j;
            if (rr < n) s += qc * tanhf(acc[ct][j] + bc);
        }
    }
#pragma unroll
    for (int m = 1; m < 64; m <<= 1) s += __shfl_xor(s, m, 64);
    __shared__ float ws[4];
    if (l == 0) ws[wid] = s;
    __syncthreads();
    if (threadIdx.x == 0)
        atomicAdd(&att_part[((blockIdx.x & 63) << 2) + ttype], ws[0] + ws[1] + ws[2] + ws[3]);
}

// ---------------- GCN aggregate (gather CSR over fp16 rows), fp16 out ----------------
// edge_dinv=1 (layer1): out[i] = relu((S_j g[pi(src_j)]*dinv[src_j] + g[pi(i)]*dinv[i])*dinv[i]+b)
// edge_dinv=0 (layer2): g pre-scaled by dinv:  out[i] = relu((S_j g[src_j] + g[i])*dinv[i]+b)
__global__ __launch_bounds__(256) void k_spmm(const f16* __restrict__ g,
                                              const int* __restrict__ csr,
                                              const int* __restrict__ rowstart,
                                              const float* __restrict__ dinv,
                                              const int* __restrict__ permp,
                                              const float* __restrict__ bias,
                                              f16* __restrict__ out,
                                              f16* __restrict__ out2,
                                              int n, int edge_dinv) {
    int gw = (int)((blockIdx.x * (long long)blockDim.x + threadIdx.x) >> 6);
    int lane = threadIdx.x & 63;
    if (gw >= n) return;
    int s0 = rowstart[gw], s1 = rowstart[gw + 1];
    float di = dinv[gw];
    size_t co = (size_t)(lane << 1);
    int self = permp ? permp[gw] : gw;
    h2v gi = *(const h2v*)(g + (size_t)self * D_ + co);
    float wself = edge_dinv ? di : 1.0f;
    float ax0 = (float)gi.x * wself, ay0 = (float)gi.y * wself;
    float ax1 = 0.f, ay1 = 0.f, ax2 = 0.f, ay2 = 0.f, ax3 = 0.f, ay3 = 0.f;
    int j = s0;
    if (edge_dinv) {
        for (; j + 8 <= s1; j += 8) {
            int s[8];
#pragma unroll
            for (int u = 0; u < 8; u++) s[u] = csr[j + u];
            float w[8];
            int rr[8];
#pragma unroll
            for (int u = 0; u < 8; u++) { w[u] = dinv[s[u]]; rr[u] = permp ? permp[s[u]] : s[u]; }
            h2v v[8];
#pragma unroll
            for (int u = 0; u < 8; u++) v[u] = *(const h2v*)(g + (size_t)rr[u] * D_ + co);
            ax0 = fmaf((float)v[0].x, w[0], ax0); ay0 = fmaf((float)v[0].y, w[0], ay0);
            ax1 = fmaf((float)v[1].x, w[1], ax1); ay1 = fmaf((float)v[1].y, w[1], ay1);
            ax2 = fmaf((float)v[2].x, w[2], ax2); ay2 = fmaf((float)v[2].y, w[2], ay2);
            ax3 = fmaf((float)v[3].x, w[3], ax3); ay3 = fmaf((float)v[3].y, w[3], ay3);
            ax0 = fmaf((float)v[4].x, w[4], ax0); ay0 = fmaf((float)v[4].y, w[4], ay0);
            ax1 = fmaf((float)v[5].x, w[5], ax1); ay1 = fmaf((float)v[5].y, w[5], ay1);
            ax2 = fmaf((float)v[6].x, w[6], ax2); ay2 = fmaf((float)v[6].y, w[6], ay2);
            ax3 = fmaf((float)v[7].x, w[7], ax3); ay3 = fmaf((float)v[7].y, w[7], ay3);
        }
        for (; j < s1; j++) {
            int s = csr[j];
            float w = dinv[s];
            int rr = permp ? permp[s] : s;
            h2v v = *(const h2v*)(g + (size_t)rr * D_ + co);
            ax0 = fmaf((float)v.x, w, ax0); ay0 = fmaf((float)v.y, w, ay0);
        }
    } else {
        for (; j + 8 <= s1; j += 8) {
            int s[8];
#pragma unroll
            for (int u = 0; u < 8; u++) s[u] = csr[j + u];
            h2v v[8];
#pragma unroll
            for (int u = 0; u < 8; u++) v[u] = *(const h2v*)(g + (size_t)s[u] * D_ + co);
            ax0 += (float)v[0].x; ay0 += (float)v[0].y;
            ax1 += (float)v[1].x; ay1 += (float)v[1].y;
            ax2 += (float)v[2].x; ay2 += (float)v[2].y;
            ax3 += (float)v[3].x; ay3 += (float)v[3].y;
            ax0 += (float)v[4].x; ay0 += (float)v[4].y;
            ax1 += (float)v[5].x; ay1 += (float)v[5].y;
            ax2 += (float)v[6].x; ay2 += (float)v[6].y;
            ax3 += (float)v[7].x; ay3 += (float)v[7].y;
        }
        for (; j < s1; j++) {
            int s = csr[j];
            h2v v = *(const h2v*)(g + (size_t)s * D_ + co);
            ax0 += (float)v.x; ay0 += (float)v.y;
        }
    }
    float ax = (ax0 + ax1) + (ax2 + ax3);
    float ay = (ay0 + ay1) + (ay2 + ay3);
    size_t base = (size_t)gw * D_ + co;
    float2 b = *(const float2*)(bias + co);
    float ox = fmaxf(fmaf(ax, di, b.x), 0.f);
    float oy = fmaxf(fmaf(ay, di, b.y), 0.f);
    h2v h;
    h.x = (f16)ox; h.y = (f16)oy;
    *(h2v*)(out + base) = h;
    if (out2 && gw < BATCH_) *(h2v*)(out2 + base) = h;
}

__global__ void k_attw(const float* __restrict__ att_part, float* __restrict__ att_w, float invN) {
    __shared__ float sb[3];
    int t = threadIdx.x;
    if (t < 3) {
        float s = 0.f;
        for (int i = 0; i < 64; i++) s += att_part[(i << 2) + t];
        sb[t] = s * invN;
    }
    __syncthreads();
    if (t == 0) {
        float m = fmaxf(sb[0], fmaxf(sb[1], sb[2]));
        float x0 = expf(sb[0] - m), x1 = expf(sb[1] - m), x2 = expf(sb[2] - m);
        float inv = 1.f / (x0 + x1 + x2);
        att_w[0] = x0 * inv; att_w[1] = x1 * inv; att_w[2] = x2 * inv;
    }
}

// ---------------- pos: column sums of combined rows (Zb fp16) ----------------
__global__ __launch_bounds__(256) void k_colsum(const f16* __restrict__ Zb, size_t BD,
                                                const float* __restrict__ att_w,
                                                float* __restrict__ colsum) {
    int c2 = threadIdx.x & 63;
    int rg = threadIdx.x >> 6;
    int nbase = blockIdx.x << 7;  // 128 rows per block, 512 blocks = 65536 rows
    float w0 = att_w[0], w1 = att_w[1], w2 = att_w[2];
    float csx = 0.f, csy = 0.f;
    for (int i = rg; i < 128; i += 4) {
        size_t off = (size_t)(nbase + i) * D_ + (c2 << 1);
        h2v z0 = *(const h2v*)(Zb + off);
        h2v z1 = *(const h2v*)(Zb + BD + off);
        h2v z2 = *(const h2v*)(Zb + 2 * BD + off);
        csx += w0 * (float)z0.x + w1 * (float)z1.x + w2 * (float)z2.x;
        csy += w0 * (float)z0.y + w1 * (float)z1.y + w2 * (float)z2.y;
    }
    __shared__ float red[4][128];
    red[rg][c2 << 1] = csx;
    red[rg][(c2 << 1) + 1] = csy;
    __syncthreads();
    if (rg == 0) {
        float sx = red[0][c2 << 1] + red[1][c2 << 1] + red[2][c2 << 1] + red[3][c2 << 1];
        float sy = red[0][(c2 << 1) + 1] + red[1][(c2 << 1) + 1] + red[2][(c2 << 1) + 1] + red[3][(c2 << 1) + 1];
        atomicAdd(&colsum[c2 << 1], sx);
        atomicAdd(&colsum[(c2 << 1) + 1], sy);
    }
}

__global__ void k_summary_c(const float* __restrict__ colsum, const float* __restrict__ sv,
                            const float* __restrict__ Wd, float* __restrict__ cvec,
                            float* __restrict__ out_summary) {
    __shared__ float sl[128];
    int t = threadIdx.x;  // 128 threads
    float s = 0.5f * (sv[t] + colsum[t] * (1.0f / (float)BATCH_));
    sl[t] = s;
    out_summary[t] = s;
    __syncthreads();
    float a = 0.f;
    for (int j = 0; j < 128; j++) a = fmaf(Wd[t * D_ + j], sl[j], a);
    cvec[t] = a;
}

// ---------------- score: combine z_t[:B] rows on the fly, dot with c ----------------
__global__ __launch_bounds__(256) void k_cscore(const f16* __restrict__ Zb, size_t BD,
                                                const float* __restrict__ att_w,
                                                const float* __restrict__ c,
                                                const float* __restrict__ bd,
                                                float* __restrict__ out, int B) {
    int gw = (int)((blockIdx.x * (long long)blockDim.x + threadIdx.x) >> 6);
    int lane = threadIdx.x & 63;
    if (gw >= B) return;
    size_t off = (size_t)gw * D_ + (lane << 1);
    float w0 = att_w[0], w1 = att_w[1], w2 = att_w[2];
    h2v z0 = *(const h2v*)(Zb + off);
    h2v z1 = *(const h2v*)(Zb + BD + off);
    h2v z2 = *(const h2v*)(Zb + 2 * BD + off);
    float vx = w0 * (float)z0.x + w1 * (float)z1.x + w2 * (float)z2.x;
    float vy = w0 * (float)z0.y + w1 * (float)z1.y + w2 * (float)z2.y;
    float2 cc = *(const float2*)(c + (lane << 1));
    float a = vx * cc.x + vy * cc.y;
#pragma unroll
    for (int m = 1; m < 64; m <<= 1) a += __shfl_xor(a, m, 64);
    if (lane == 0) out[gw] = a + bd[0];
}

// ---------------- host launcher ----------------
extern "C" void kernel_launch(void* const* d_in, const int* in_sizes, int n_in,
                              void* d_out, int out_size, void* d_ws, size_t ws_size,
                              hipStream_t stream) {
    const float* x      = (const float*)d_in[0];
    const int*   ei     = (const int*)d_in[1];    // int32 on device
    const int*   perm   = (const int*)d_in[2];    // int32 on device
    const float* sv     = (const float*)d_in[3];
    const float* W_lin  = (const float*)d_in[5];
    const float* b_lin  = (const float*)d_in[6];
    const float* W1     = (const float*)d_in[7];
    const float* b1     = (const float*)d_in[8];
    const float* W2     = (const float*)d_in[9];
    const float* b2     = (const float*)d_in[10];
    const float* W_sem  = (const float*)d_in[11];
    const float* b_sem  = (const float*)d_in[12];
    const float* q_sem  = (const float*)d_in[13];
    const float* W_disc = (const float*)d_in[14];
    const float* b_disc = (const float*)d_in[15];
    float* out = (float*)d_out;

    int N = in_sizes[0] / D_;
    int E = in_sizes[1] / 6;
    int L = 3 * N;
    size_t ND = (size_t)N * D_;
    size_t BD = (size_t)BATCH_ * D_;
    int B = BATCH_;

    char* ws = (char*)d_ws;
    size_t o = 0;
    auto alloc = [&](size_t bytes) -> char* {
        char* p = ws + o;
        o = (o + bytes + 255) & ~(size_t)255;
        return p;
    };
    float* dinv     = (float*)alloc((size_t)L * 4);
    int*   cnt      = (int*)alloc((size_t)L * 4);
    int*   rowstart = (int*)alloc(((size_t)L + 1) * 4);
    int*   csr      = (int*)alloc((size_t)3 * E * 4);
    int*   bsum     = (int*)alloc(1024 * 4);
    int*   bscan    = (int*)alloc(1024 * 4);
    float* att_part = (float*)alloc(256 * 4);
    float* att_w    = (float*)alloc(16 * 4);   // [0..2]=pos, [8..10]=neg
    float* colsum   = (float*)alloc(128 * 4);
    float* cvec     = (float*)alloc(128 * 4);
    f16*   Wlt      = (f16*)alloc(128 * 128 * 2);
    f16*   W1t      = (f16*)alloc(128 * 128 * 2);
    f16*   W2t      = (f16*)alloc(128 * 128 * 2);
    f16*   Wst      = (f16*)alloc(128 * 128 * 2);
    f16*   Zb       = (f16*)alloc(3 * BD * 2);    // z_t[:B] per type, fp16
    f16*   Ah       = (f16*)alloc(ND * 2);        // relu(x@Wlin+b) fp16
    f16*   G1h      = (f16*)alloc(ND * 2);        // A@W1, unscaled fp16 (shared both branches)
    f16*   G2h      = (f16*)alloc(ND * 2);        // (h1@W2)*dinv fp16
    f16*   H16      = (f16*)alloc(ND * 2);        // h1 / z scratch fp16
    size_t o_full = o;

    if (o_full > ws_size) {
        k_sentinel<<<256, 256, 0, stream>>>(out, out_size);
        return;
    }

    // weight transposes (f32 -> f16, [c][k])
    k_wt<<<64, 256, 0, stream>>>(W_lin, Wlt);
    k_wt<<<64, 256, 0, stream>>>(W1, W1t);
    k_wt<<<64, 256, 0, stream>>>(W2, W2t);
    k_wt<<<64, 256, 0, stream>>>(W_sem, Wst);

    // ---- CSR build (by destination), per edge type ----
    k_zero32<<<256, 256, 0, stream>>>((uint32_t*)cnt, L);
    k_count<<<2048, 256, 0, stream>>>(ei, cnt, N, E);
    k_dinv<<<(L + 255) / 256, 256, 0, stream>>>(cnt, dinv, L);
    int nb = (L + 511) / 512;
    k_scan1<<<nb, 512, 0, stream>>>(cnt, rowstart, bsum, L);
    k_scan2<<<1, 1024, 0, stream>>>(bsum, bscan, nb);
    k_scan3<<<(L + 255) / 256, 256, 0, stream>>>(rowstart, bscan, L, 3 * E);
    k_zero32<<<256, 256, 0, stream>>>((uint32_t*)cnt, L);
    k_fill<<<2048, 256, 0, stream>>>(ei, rowstart, cnt, csr, N, E);

    int mg_grid = (N + 63) / 64;
    int spmm_grid = (N + 3) / 4;
    int scoreB_grid = (B + 3) / 4;

    // shared across branches: A = relu(x@Wlin+b);  G1 = A@W1 (fp16, unscaled)
    k_mgemm<<<mg_grid, 256, 0, stream>>>(x, 1, Wlt, b_lin, nullptr, Ah, N, 1);
    k_mgemm<<<mg_grid, 256, 0, stream>>>(Ah, 0, W1t, nullptr, nullptr, G1h, N, 0);

    for (int br = 0; br < 2; br++) {
        const int* permp = br ? perm : nullptr;
        float* aw = att_w + br * 8;
        k_zero32<<<1, 256, 0, stream>>>((uint32_t*)att_part, 256);
        for (int t3 = 0; t3 < 3; t3++) {
            const int* rs = rowstart + (size_t)t3 * N;
            const float* dv = dinv + (size_t)t3 * N;
            f16* Zbt = Zb + (size_t)t3 * BD;
            // h1 = relu(agg_t(G1[perm]) * dinv + b1)
            k_spmm<<<spmm_grid, 256, 0, stream>>>(G1h, csr, rs, dv, permp, b1, H16, nullptr, N, 1);
            // G2 = (h1 @ W2) * dinv, fp16
            k_mgemm<<<mg_grid, 256, 0, stream>>>(H16, 0, W2t, nullptr, dv, G2h, N, 0);
            // z_t = relu(agg_t(G2) * dinv + b2)  (pre-scaled)
            k_spmm<<<spmm_grid, 256, 0, stream>>>(G2h, csr, rs, dv, nullptr, b2, H16, Zbt, N, 0);
            // attention partial scores over all N rows of z_t
            k_matt<<<mg_grid, 256, 0, stream>>>(H16, Wst, b_sem, q_sem, att_part, N, t3);
        }
        k_attw<<<1, 64, 0, stream>>>(att_part, aw, 1.0f / (float)N);
        if (br == 0) {
            k_zero32<<<1, 256, 0, stream>>>((uint32_t*)colsum, 128);
            k_colsum<<<512, 256, 0, stream>>>(Zb, BD, aw, colsum);
            k_summary_c<<<1, 128, 0, stream>>>(colsum, sv, W_disc, cvec, out + 2 * (size_t)B);
            k_cscore<<<scoreB_grid, 256, 0, stream>>>(Zb, BD, aw, cvec, b_disc, out, B);
        } else {
            k_cscore<<<scoreB_grid, 256, 0, stream>>>(Zb, BD, aw, cvec, b_disc, out + B, B);
        }
    }
}

// Round 6
// 1895.244 us; speedup vs baseline: 2.1091x; 1.1061x over previous
//
#include <hip/hip_runtime.h>

#define D_ 128
#define BATCH_ 65536

typedef _Float16 f16;
typedef _Float16 h2v __attribute__((ext_vector_type(2)));
typedef _Float16 h4v __attribute__((ext_vector_type(4)));
typedef _Float16 f16x8 __attribute__((ext_vector_type(8)));
typedef float f32x4 __attribute__((ext_vector_type(4)));

// ---------------- utility ----------------
__global__ void k_zero32(uint32_t* p, long long n) {
    long long i = (long long)blockIdx.x * blockDim.x + threadIdx.x;
    long long st = (long long)gridDim.x * blockDim.x;
    for (; i < n; i += st) p[i] = 0u;
}

__global__ void k_sentinel(float* p, long long n) {
    long long i = (long long)blockIdx.x * blockDim.x + threadIdx.x;
    long long st = (long long)gridDim.x * blockDim.x;
    for (; i < n; i += st) p[i] = -12345.0f;
}

// transpose+convert 128x128 weight: Wt[c][k] = (f16)W[k][c]
__global__ void k_wt(const float* __restrict__ W, f16* __restrict__ Wt) {
    int t = blockIdx.x * 256 + threadIdx.x;  // grid 64 -> 16384
    int k = t >> 7, c = t & 127;
    Wt[c * 128 + k] = (f16)W[k * 128 + c];
}

// row gather: dst[i][:] = src[perm[i]][:]   (fp16 rows as u32 pairs)
__global__ void k_gath(const uint32_t* __restrict__ src, const int* __restrict__ perm,
                       uint32_t* __restrict__ dst, int N) {
    int i = blockIdx.x * 256 + threadIdx.x;  // over N*64 u32
    if (i >= N * 64) return;
    int row = i >> 6, col = i & 63;
    dst[i] = src[((size_t)perm[row] << 6) + col];
}

// ---------------- CSR build (edge_index is int32 on device) ----------------
__global__ void k_count(const int* __restrict__ ei, int* __restrict__ cnt, int N, int E) {
    long long i = (long long)blockIdx.x * blockDim.x + threadIdx.x;
    long long st = (long long)gridDim.x * blockDim.x;
    long long tot = 3LL * E;
    for (; i < tot; i += st) {
        int t = (int)(i / E);
        int w = (int)(i - (long long)t * E);
        int dst = ei[(long long)t * 2 * E + E + w];
        atomicAdd(&cnt[t * N + dst], 1);
    }
}

__global__ void k_dinv(const int* __restrict__ cnt, float* __restrict__ dinv, int L) {
    int i = blockIdx.x * blockDim.x + threadIdx.x;
    if (i < L) dinv[i] = rsqrtf((float)cnt[i] + 1.0f);
}

__global__ void k_scan1(const int* __restrict__ in, int* __restrict__ excl,
                        int* __restrict__ bsum, int L) {
    __shared__ int s[512];
    int t = threadIdx.x;
    int g = blockIdx.x * 512 + t;
    int v = (g < L) ? in[g] : 0;
    s[t] = v;
    __syncthreads();
    for (int off = 1; off < 512; off <<= 1) {
        int a = (t >= off) ? s[t - off] : 0;
        __syncthreads();
        s[t] += a;
        __syncthreads();
    }
    if (g < L) excl[g] = s[t] - v;
    if (t == 511) bsum[blockIdx.x] = s[511];
}

__global__ void k_scan2(const int* __restrict__ bsum, int* __restrict__ bscan, int nb) {
    __shared__ int s[1024];
    int t = threadIdx.x;
    int v = (t < nb) ? bsum[t] : 0;
    s[t] = v;
    __syncthreads();
    for (int off = 1; off < 1024; off <<= 1) {
        int a = (t >= off) ? s[t - off] : 0;
        __syncthreads();
        s[t] += a;
        __syncthreads();
    }
    bscan[t] = s[t] - v;  // exclusive
}

__global__ void k_scan3(int* __restrict__ excl, const int* __restrict__ bscan, int L, int total) {
    int g = blockIdx.x * blockDim.x + threadIdx.x;
    if (g < L) excl[g] += bscan[g >> 9];
    if (g == 0) excl[L] = total;
}

__global__ void k_fill(const int* __restrict__ ei, const int* __restrict__ rowstart,
                       int* __restrict__ cur, int* __restrict__ csr, int N, int E) {
    long long i = (long long)blockIdx.x * blockDim.x + threadIdx.x;
    long long st = (long long)gridDim.x * blockDim.x;
    long long tot = 3LL * E;
    for (; i < tot; i += st) {
        int t = (int)(i / E);
        int w = (int)(i - (long long)t * E);
        int src = ei[(long long)t * 2 * E + w];
        int dst = ei[(long long)t * 2 * E + E + w];
        int r = t * N + dst;
        int pos = rowstart[r] + atomicAdd(&cur[r], 1);
        csr[pos] = src;
    }
}

// ---------------- MFMA GEMM: out(f16) = [relu](in @ W [+ bias]) [* scale[row]] ----------------
// in: row-major [n][128] f32 or f16; Wt: [c][k] f16. In-place (in==out) is safe: each block
// reads only its own 64 rows before writing them.
__global__ __launch_bounds__(256) void k_mgemm(const void* __restrict__ in, int in_f32,
                                               const f16* __restrict__ Wt,
                                               const float* __restrict__ bias,
                                               const float* __restrict__ scale,
                                               f16* __restrict__ outh, int n, int relu) {
    int l = threadIdx.x & 63, wid = threadIdx.x >> 6;
    int row0 = blockIdx.x * 64 + wid * 16;
    int r = l & 15, kg = l >> 4;
    int arow = row0 + r;
    f32x4 acc[8] = {};
#pragma unroll
    for (int kk = 0; kk < 4; kk++) {
        int off = kk * 32 + kg * 8;
        f16x8 a = {};
        if (arow < n) {
            if (in_f32) {
                const float* inf = (const float*)in + (size_t)arow * D_ + off;
                float4 v0 = *(const float4*)inf;
                float4 v1 = *(const float4*)(inf + 4);
                a[0] = (f16)v0.x; a[1] = (f16)v0.y; a[2] = (f16)v0.z; a[3] = (f16)v0.w;
                a[4] = (f16)v1.x; a[5] = (f16)v1.y; a[6] = (f16)v1.z; a[7] = (f16)v1.w;
            } else {
                a = *(const f16x8*)((const f16*)in + (size_t)arow * D_ + off);
            }
        }
#pragma unroll
        for (int ct = 0; ct < 8; ct++) {
            int c = ct * 16 + r;
            f16x8 b = *(const f16x8*)(Wt + (size_t)c * D_ + off);
            acc[ct] = __builtin_amdgcn_mfma_f32_16x16x32_f16(a, b, acc[ct], 0, 0, 0);
        }
    }
    // epilogue: C/D layout row=(l>>4)*4+j, col=l&15
    float sc[4];
#pragma unroll
    for (int j = 0; j < 4; j++) {
        int rr = row0 + kg * 4 + j;
        sc[j] = (scale && rr < n) ? scale[rr] : 1.0f;
    }
#pragma unroll
    for (int ct = 0; ct < 8; ct++) {
        int c = ct * 16 + r;
        float bs = bias ? bias[c] : 0.0f;
#pragma unroll
        for (int j = 0; j < 4; j++) {
            int rr = row0 + kg * 4 + j;
            if (rr >= n) continue;
            float o = acc[ct][j] + bs;
            if (relu) o = fmaxf(o, 0.0f);
            o *= sc[j];
            outh[(size_t)rr * D_ + c] = (f16)o;
        }
    }
}

// ---------------- MFMA semantic attention: sum_r q . tanh(z_r @ Wsem + bsem) ----------------
__global__ __launch_bounds__(256) void k_matt(const f16* __restrict__ z,
                                              const f16* __restrict__ Wst,
                                              const float* __restrict__ bsem,
                                              const float* __restrict__ q,
                                              float* __restrict__ att_part, int n, int ttype) {
    int l = threadIdx.x & 63, wid = threadIdx.x >> 6;
    int row0 = blockIdx.x * 64 + wid * 16;
    int r = l & 15, kg = l >> 4;
    int arow = row0 + r;
    f32x4 acc[8] = {};
#pragma unroll
    for (int kk = 0; kk < 4; kk++) {
        int off = kk * 32 + kg * 8;
        f16x8 a = {};
        if (arow < n) a = *(const f16x8*)(z + (size_t)arow * D_ + off);
#pragma unroll
        for (int ct = 0; ct < 8; ct++) {
            int c = ct * 16 + r;
            f16x8 b = *(const f16x8*)(Wst + (size_t)c * D_ + off);
            acc[ct] = __builtin_amdgcn_mfma_f32_16x16x32_f16(a, b, acc[ct], 0, 0, 0);
        }
    }
    float s = 0.0f;
#pragma unroll
    for (int ct = 0; ct < 8; ct++) {
        int c = ct * 16 + r;
        float qc = q[c], bc = bsem[c];
#pragma unroll
        for (int j = 0; j < 4; j++) {
            int rr = row0 + kg * 4 + j;
            if (rr < n) s += qc * tanhf(acc[ct][j] + bc);
        }
    }
#pragma unroll
    for (int m = 1; m < 64; m <<= 1) s += __shfl_xor(s, m, 64);
    __shared__ float ws[4];
    if (l == 0) ws[wid] = s;
    __syncthreads();
    if (threadIdx.x == 0)
        atomicAdd(&att_part[((blockIdx.x & 63) << 2) + ttype], ws[0] + ws[1] + ws[2] + ws[3]);
}

// ---------------- GCN aggregate, batched over 3 types (rows = 3N) ----------------
// Half-wave split: lanes 0-31 handle edges j..j+3, lanes 32-63 j+4..j+7; each lane
// loads h4v (4 cols). Halves combined with one shfl_xor(32) at the end.
// edge_dinv=1: w_e = dinv[tbase+s], self weight di;  edge_dinv=0: pre-scaled, w=1.
// src row = (src_typed? tbase:0) + s;  self = (src_typed? gw : gw-tbase).
__global__ __launch_bounds__(256) void k_spmm(const f16* __restrict__ gsrc,
                                              const int* __restrict__ csr,
                                              const int* __restrict__ rowstart,
                                              const float* __restrict__ dinv,
                                              const float* __restrict__ bias,
                                              f16* __restrict__ outh,
                                              int N, int rows, int edge_dinv, int src_typed) {
    int gw = (int)((blockIdx.x * (long long)blockDim.x + threadIdx.x) >> 6);
    int l = threadIdx.x & 63;
    if (gw >= rows) return;
    int half = l >> 5, lp = l & 31;
    int t = gw / N;
    int tbase = t * N;
    int sbase = src_typed ? tbase : 0;
    int self = src_typed ? gw : (gw - tbase);
    int s0 = rowstart[gw], s1 = rowstart[gw + 1];
    float di = dinv[gw];
    size_t co = (size_t)(lp << 2);
    float a0 = 0.f, a1 = 0.f, a2 = 0.f, a3 = 0.f;
    if (half == 0) {
        h4v sv = *(const h4v*)(gsrc + (size_t)self * D_ + co);
        float wsf = edge_dinv ? di : 1.0f;
        a0 = (float)sv[0] * wsf; a1 = (float)sv[1] * wsf;
        a2 = (float)sv[2] * wsf; a3 = (float)sv[3] * wsf;
    }
    int j = s0;
    if (edge_dinv) {
        for (; j + 8 <= s1; j += 8) {
            int4 iv = *(const int4*)(csr + j + (half << 2));
            float w0 = dinv[tbase + iv.x], w1 = dinv[tbase + iv.y];
            float w2 = dinv[tbase + iv.z], w3 = dinv[tbase + iv.w];
            h4v v0 = *(const h4v*)(gsrc + (size_t)(sbase + iv.x) * D_ + co);
            h4v v1 = *(const h4v*)(gsrc + (size_t)(sbase + iv.y) * D_ + co);
            h4v v2 = *(const h4v*)(gsrc + (size_t)(sbase + iv.z) * D_ + co);
            h4v v3 = *(const h4v*)(gsrc + (size_t)(sbase + iv.w) * D_ + co);
            a0 = fmaf((float)v0[0], w0, a0); a1 = fmaf((float)v0[1], w0, a1);
            a2 = fmaf((float)v0[2], w0, a2); a3 = fmaf((float)v0[3], w0, a3);
            a0 = fmaf((float)v1[0], w1, a0); a1 = fmaf((float)v1[1], w1, a1);
            a2 = fmaf((float)v1[2], w1, a2); a3 = fmaf((float)v1[3], w1, a3);
            a0 = fmaf((float)v2[0], w2, a0); a1 = fmaf((float)v2[1], w2, a1);
            a2 = fmaf((float)v2[2], w2, a2); a3 = fmaf((float)v2[3], w2, a3);
            a0 = fmaf((float)v3[0], w3, a0); a1 = fmaf((float)v3[1], w3, a1);
            a2 = fmaf((float)v3[2], w3, a2); a3 = fmaf((float)v3[3], w3, a3);
        }
        if (j < s1) {
#pragma unroll
            for (int u = 0; u < 4; u++) {
                int e = j + (half << 2) + u;
                if (e < s1) {
                    int s = csr[e];
                    float w = dinv[tbase + s];
                    h4v v = *(const h4v*)(gsrc + (size_t)(sbase + s) * D_ + co);
                    a0 = fmaf((float)v[0], w, a0); a1 = fmaf((float)v[1], w, a1);
                    a2 = fmaf((float)v[2], w, a2); a3 = fmaf((float)v[3], w, a3);
                }
            }
        }
    } else {
        for (; j + 8 <= s1; j += 8) {
            int4 iv = *(const int4*)(csr + j + (half << 2));
            h4v v0 = *(const h4v*)(gsrc + (size_t)(sbase + iv.x) * D_ + co);
            h4v v1 = *(const h4v*)(gsrc + (size_t)(sbase + iv.y) * D_ + co);
            h4v v2 = *(const h4v*)(gsrc + (size_t)(sbase + iv.z) * D_ + co);
            h4v v3 = *(const h4v*)(gsrc + (size_t)(sbase + iv.w) * D_ + co);
            a0 += (float)v0[0] + (float)v1[0] + (float)v2[0] + (float)v3[0];
            a1 += (float)v0[1] + (float)v1[1] + (float)v2[1] + (float)v3[1];
            a2 += (float)v0[2] + (float)v1[2] + (float)v2[2] + (float)v3[2];
            a3 += (float)v0[3] + (float)v1[3] + (float)v2[3] + (float)v3[3];
        }
        if (j < s1) {
#pragma unroll
            for (int u = 0; u < 4; u++) {
                int e = j + (half << 2) + u;
                if (e < s1) {
                    int s = csr[e];
                    h4v v = *(const h4v*)(gsrc + (size_t)(sbase + s) * D_ + co);
                    a0 += (float)v[0]; a1 += (float)v[1];
                    a2 += (float)v[2]; a3 += (float)v[3];
                }
            }
        }
    }
    a0 += __shfl_xor(a0, 32, 64);
    a1 += __shfl_xor(a1, 32, 64);
    a2 += __shfl_xor(a2, 32, 64);
    a3 += __shfl_xor(a3, 32, 64);
    if (half == 0) {
        float4 b = *(const float4*)(bias + (lp << 2));
        h4v o;
        o[0] = (f16)fmaxf(fmaf(a0, di, b.x), 0.f);
        o[1] = (f16)fmaxf(fmaf(a1, di, b.y), 0.f);
        o[2] = (f16)fmaxf(fmaf(a2, di, b.z), 0.f);
        o[3] = (f16)fmaxf(fmaf(a3, di, b.w), 0.f);
        *(h4v*)(outh + (size_t)gw * D_ + co) = o;
    }
}

__global__ void k_attw(const float* __restrict__ att_part, float* __restrict__ att_w, float invN) {
    __shared__ float sb[3];
    int t = threadIdx.x;
    if (t < 3) {
        float s = 0.f;
        for (int i = 0; i < 64; i++) s += att_part[(i << 2) + t];
        sb[t] = s * invN;
    }
    __syncthreads();
    if (t == 0) {
        float m = fmaxf(sb[0], fmaxf(sb[1], sb[2]));
        float x0 = expf(sb[0] - m), x1 = expf(sb[1] - m), x2 = expf(sb[2] - m);
        float inv = 1.f / (x0 + x1 + x2);
        att_w[0] = x0 * inv; att_w[1] = x1 * inv; att_w[2] = x2 * inv;
    }
}

// ---------------- pos: column sums of combined rows (Z fp16, typed slices) ----------------
__global__ __launch_bounds__(256) void k_colsum(const f16* __restrict__ Z, size_t tstride,
                                                const float* __restrict__ att_w,
                                                float* __restrict__ colsum) {
    int c2 = threadIdx.x & 63;
    int rg = threadIdx.x >> 6;
    int nbase = blockIdx.x << 7;  // 128 rows per block, 512 blocks = 65536 rows
    float w0 = att_w[0], w1 = att_w[1], w2 = att_w[2];
    float csx = 0.f, csy = 0.f;
    for (int i = rg; i < 128; i += 4) {
        size_t off = (size_t)(nbase + i) * D_ + (c2 << 1);
        h2v z0 = *(const h2v*)(Z + off);
        h2v z1 = *(const h2v*)(Z + tstride + off);
        h2v z2 = *(const h2v*)(Z + 2 * tstride + off);
        csx += w0 * (float)z0.x + w1 * (float)z1.x + w2 * (float)z2.x;
        csy += w0 * (float)z0.y + w1 * (float)z1.y + w2 * (float)z2.y;
    }
    __shared__ float red[4][128];
    red[rg][c2 << 1] = csx;
    red[rg][(c2 << 1) + 1] = csy;
    __syncthreads();
    if (rg == 0) {
        float sx = red[0][c2 << 1] + red[1][c2 << 1] + red[2][c2 << 1] + red[3][c2 << 1];
        float sy = red[0][(c2 << 1) + 1] + red[1][(c2 << 1) + 1] + red[2][(c2 << 1) + 1] + red[3][(c2 << 1) + 1];
        atomicAdd(&colsum[c2 << 1], sx);
        atomicAdd(&colsum[(c2 << 1) + 1], sy);
    }
}

__global__ void k_summary_c(const float* __restrict__ colsum, const float* __restrict__ sv,
                            const float* __restrict__ Wd, float* __restrict__ cvec,
                            float* __restrict__ out_summary) {
    __shared__ float sl[128];
    int t = threadIdx.x;  // 128 threads
    float s = 0.5f * (sv[t] + colsum[t] * (1.0f / (float)BATCH_));
    sl[t] = s;
    out_summary[t] = s;
    __syncthreads();
    float a = 0.f;
    for (int j = 0; j < 128; j++) a = fmaf(Wd[t * D_ + j], sl[j], a);
    cvec[t] = a;
}

// ---------------- score: combine z_t[:B] rows on the fly, dot with c ----------------
__global__ __launch_bounds__(256) void k_cscore(const f16* __restrict__ Z, size_t tstride,
                                                const float* __restrict__ att_w,
                                                const float* __restrict__ c,
                                                const float* __restrict__ bd,
                                                float* __restrict__ out, int B) {
    int gw = (int)((blockIdx.x * (long long)blockDim.x + threadIdx.x) >> 6);
    int lane = threadIdx.x & 63;
    if (gw >= B) return;
    size_t off = (size_t)gw * D_ + (lane << 1);
    float w0 = att_w[0], w1 = att_w[1], w2 = att_w[2];
    h2v z0 = *(const h2v*)(Z + off);
    h2v z1 = *(const h2v*)(Z + tstride + off);
    h2v z2 = *(const h2v*)(Z + 2 * tstride + off);
    float vx = w0 * (float)z0.x + w1 * (float)z1.x + w2 * (float)z2.x;
    float vy = w0 * (float)z0.y + w1 * (float)z1.y + w2 * (float)z2.y;
    float2 cc = *(const float2*)(c + (lane << 1));
    float a = vx * cc.x + vy * cc.y;
#pragma unroll
    for (int m = 1; m < 64; m <<= 1) a += __shfl_xor(a, m, 64);
    if (lane == 0) out[gw] = a + bd[0];
}

// ---------------- host launcher ----------------
extern "C" void kernel_launch(void* const* d_in, const int* in_sizes, int n_in,
                              void* d_out, int out_size, void* d_ws, size_t ws_size,
                              hipStream_t stream) {
    const float* x      = (const float*)d_in[0];
    const int*   ei     = (const int*)d_in[1];    // int32 on device
    const int*   perm   = (const int*)d_in[2];    // int32 on device
    const float* sv     = (const float*)d_in[3];
    const float* W_lin  = (const float*)d_in[5];
    const float* b_lin  = (const float*)d_in[6];
    const float* W1     = (const float*)d_in[7];
    const float* b1     = (const float*)d_in[8];
    const float* W2     = (const float*)d_in[9];
    const float* b2     = (const float*)d_in[10];
    const float* W_sem  = (const float*)d_in[11];
    const float* b_sem  = (const float*)d_in[12];
    const float* q_sem  = (const float*)d_in[13];
    const float* W_disc = (const float*)d_in[14];
    const float* b_disc = (const float*)d_in[15];
    float* out = (float*)d_out;

    int N = in_sizes[0] / D_;
    int E = in_sizes[1] / 6;
    int L = 3 * N;
    size_t ND = (size_t)N * D_;
    int B = BATCH_;

    char* ws = (char*)d_ws;
    size_t o = 0;
    auto alloc = [&](size_t bytes) -> char* {
        char* p = ws + o;
        o = (o + bytes + 255) & ~(size_t)255;
        return p;
    };
    float* dinv     = (float*)alloc((size_t)L * 4);
    int*   cnt      = (int*)alloc((size_t)L * 4);
    int*   rowstart = (int*)alloc(((size_t)L + 1) * 4);
    int*   csr      = (int*)alloc(((size_t)3 * E + 8) * 4);
    int*   bsum     = (int*)alloc(1024 * 4);
    int*   bscan    = (int*)alloc(1024 * 4);
    float* att_part = (float*)alloc(256 * 4);
    float* att_w    = (float*)alloc(16 * 4);   // [0..2]=pos, [8..10]=neg
    float* colsum   = (float*)alloc(128 * 4);
    float* cvec     = (float*)alloc(128 * 4);
    f16*   Wlt      = (f16*)alloc(128 * 128 * 2);
    f16*   W1t      = (f16*)alloc(128 * 128 * 2);
    f16*   W2t      = (f16*)alloc(128 * 128 * 2);
    f16*   Wst      = (f16*)alloc(128 * 128 * 2);
    f16*   Ah       = (f16*)alloc(ND * 2);        // relu(x@Wlin+b) fp16
    f16*   G1h      = (f16*)alloc(ND * 2);        // A@W1, unscaled fp16 (shared)
    f16*   G1p      = (f16*)alloc(ND * 2);        // G1h[perm]
    f16*   H1all    = (f16*)alloc(3 * ND * 2);    // h1 (3 types), reused in-place as G2
    f16*   Zall     = (f16*)alloc(3 * ND * 2);    // z (3 types)
    size_t o_full = o;

    if (o_full > ws_size) {
        k_sentinel<<<256, 256, 0, stream>>>(out, out_size);
        return;
    }

    // weight transposes (f32 -> f16, [c][k])
    k_wt<<<64, 256, 0, stream>>>(W_lin, Wlt);
    k_wt<<<64, 256, 0, stream>>>(W1, W1t);
    k_wt<<<64, 256, 0, stream>>>(W2, W2t);
    k_wt<<<64, 256, 0, stream>>>(W_sem, Wst);

    // ---- CSR build (by destination), per edge type ----
    k_zero32<<<256, 256, 0, stream>>>((uint32_t*)cnt, L);
    k_count<<<2048, 256, 0, stream>>>(ei, cnt, N, E);
    k_dinv<<<(L + 255) / 256, 256, 0, stream>>>(cnt, dinv, L);
    int nb = (L + 511) / 512;
    k_scan1<<<nb, 512, 0, stream>>>(cnt, rowstart, bsum, L);
    k_scan2<<<1, 1024, 0, stream>>>(bsum, bscan, nb);
    k_scan3<<<(L + 255) / 256, 256, 0, stream>>>(rowstart, bscan, L, 3 * E);
    k_zero32<<<256, 256, 0, stream>>>((uint32_t*)cnt, L);
    k_fill<<<2048, 256, 0, stream>>>(ei, rowstart, cnt, csr, N, E);

    int mgN_grid  = (N + 63) / 64;
    int mgL_grid  = (L + 63) / 64;
    int spmm_grid = (L + 3) / 4;
    int scoreB_grid = (B + 3) / 4;

    // shared: A = relu(x@Wlin+b);  G1 = A@W1;  G1p = G1[perm]
    k_mgemm<<<mgN_grid, 256, 0, stream>>>(x, 1, Wlt, b_lin, nullptr, Ah, N, 1);
    k_mgemm<<<mgN_grid, 256, 0, stream>>>(Ah, 0, W1t, nullptr, nullptr, G1h, N, 0);
    k_gath<<<(N * 64 + 255) / 256, 256, 0, stream>>>((const uint32_t*)G1h, perm,
                                                     (uint32_t*)G1p, N);

    for (int br = 0; br < 2; br++) {
        const f16* src1 = br ? G1p : G1h;
        float* aw = att_w + br * 8;
        k_zero32<<<1, 256, 0, stream>>>((uint32_t*)att_part, 256);
        // h1 (all 3 types): relu((Σ G1[s]*dinv_t[s] + G1[i]*dinv_t[i])*dinv_t[i] + b1)
        k_spmm<<<spmm_grid, 256, 0, stream>>>(src1, csr, rowstart, dinv, b1,
                                              H1all, N, L, 1, 0);
        // G2 = (h1 @ W2) * dinv  (in-place, all 3 types)
        k_mgemm<<<mgL_grid, 256, 0, stream>>>(H1all, 0, W2t, nullptr, dinv, H1all, L, 0);
        // z (all 3 types): relu((Σ G2_t[s] + G2_t[i])*dinv_t[i] + b2)
        k_spmm<<<spmm_grid, 256, 0, stream>>>(H1all, csr, rowstart, dinv, b2,
                                              Zall, N, L, 0, 1);
        for (int t3 = 0; t3 < 3; t3++)
            k_matt<<<mgN_grid, 256, 0, stream>>>(Zall + (size_t)t3 * ND, Wst, b_sem, q_sem,
                                                 att_part, N, t3);
        k_attw<<<1, 64, 0, stream>>>(att_part, aw, 1.0f / (float)N);
        if (br == 0) {
            k_zero32<<<1, 256, 0, stream>>>((uint32_t*)colsum, 128);
            k_colsum<<<512, 256, 0, stream>>>(Zall, ND, aw, colsum);
            k_summary_c<<<1, 128, 0, stream>>>(colsum, sv, W_disc, cvec, out + 2 * (size_t)B);
            k_cscore<<<scoreB_grid, 256, 0, stream>>>(Zall, ND, aw, cvec, b_disc, out, B);
        } else {
            k_cscore<<<scoreB_grid, 256, 0, stream>>>(Zall, ND, aw, cvec, b_disc, out + B, B);
        }
    }
}

// Round 7
// 1738.390 us; speedup vs baseline: 2.2994x; 1.0902x over previous
//
#include <hip/hip_runtime.h>

#define D_ 128
#define BATCH_ 65536
#define BSH 10          // bucket = 1024 destinations
#define TILE_ 16384     // edges per scatter block

typedef _Float16 f16;
typedef _Float16 h2v __attribute__((ext_vector_type(2)));
typedef _Float16 h4v __attribute__((ext_vector_type(4)));
typedef _Float16 f16x8 __attribute__((ext_vector_type(8)));
typedef float f32x4 __attribute__((ext_vector_type(4)));

// ---------------- utility ----------------
__global__ void k_zero32(uint32_t* p, long long n) {
    long long i = (long long)blockIdx.x * blockDim.x + threadIdx.x;
    long long st = (long long)gridDim.x * blockDim.x;
    for (; i < n; i += st) p[i] = 0u;
}

__global__ void k_sentinel(float* p, long long n) {
    long long i = (long long)blockIdx.x * blockDim.x + threadIdx.x;
    long long st = (long long)gridDim.x * blockDim.x;
    for (; i < n; i += st) p[i] = -12345.0f;
}

// transpose+convert 128x128 weight: Wt[c][k] = (f16)W[k][c]
__global__ void k_wt(const float* __restrict__ W, f16* __restrict__ Wt) {
    int t = blockIdx.x * 256 + threadIdx.x;
    int k = t >> 7, c = t & 127;
    Wt[c * 128 + k] = (f16)W[k * 128 + c];
}

// row gather: dst[i][:] = src[perm[i]][:]   (fp16 rows as u32 pairs)
__global__ void k_gath(const uint32_t* __restrict__ src, const int* __restrict__ perm,
                       uint32_t* __restrict__ dst, int N) {
    int i = blockIdx.x * 256 + threadIdx.x;
    if (i >= N * 64) return;
    int row = i >> 6, col = i & 63;
    dst[i] = src[((size_t)perm[row] << 6) + col];
}

// ---------------- bucketed CSR build ----------------
// pass A: histogram edges into NBUK buckets (bucket = t*nbt + (dst>>BSH))
__global__ void k_hist(const int* __restrict__ ei, int* __restrict__ bcnt,
                       int E, int nbt, int nbuk) {
    __shared__ int hist[512];
    for (int i = threadIdx.x; i < 512; i += 256) hist[i] = 0;
    __syncthreads();
    long long tot = 3LL * E;
    long long i = (long long)blockIdx.x * 256 + threadIdx.x;
    long long st = (long long)gridDim.x * 256;
    for (; i < tot; i += st) {
        int t = (i >= E) + (i >= 2LL * E);
        long long w = i - (long long)t * E;
        int dst = ei[(long long)t * 2 * E + E + w];
        atomicAdd(&hist[t * nbt + (dst >> BSH)], 1);
    }
    __syncthreads();
    for (int i2 = threadIdx.x; i2 < nbuk; i2 += 256)
        if (hist[i2]) atomicAdd(&bcnt[i2], hist[i2]);
}

// pass B: exclusive scan of bucket counts (1 block, 512 threads)
__global__ void k_bscan(const int* __restrict__ bcnt, int* __restrict__ bbase,
                        int* __restrict__ bcur, int nbuk) {
    __shared__ int s[512];
    int t = threadIdx.x;
    int v = (t < nbuk) ? bcnt[t] : 0;
    s[t] = v;
    __syncthreads();
    for (int off = 1; off < 512; off <<= 1) {
        int a = (t >= off) ? s[t - off] : 0;
        __syncthreads();
        s[t] += a;
        __syncthreads();
    }
    if (t < nbuk) {
        int e = s[t] - v;
        bbase[t] = e;
        bcur[t] = e;
        if (t == nbuk - 1) bbase[nbuk] = s[t];
    }
}

// pass C: scatter packed (src | d<<22) into bucket regions, per-block reservations
__global__ __launch_bounds__(256) void k_scatter(const int* __restrict__ ei,
                                                 int* __restrict__ bcur,
                                                 uint32_t* __restrict__ pairs,
                                                 int E, int nbt, int nbuk) {
    __shared__ int hist[512];
    __shared__ int base[512];
    long long tot = 3LL * E;
    long long w0 = (long long)blockIdx.x * TILE_;
    long long w1 = w0 + TILE_ < tot ? w0 + TILE_ : tot;
    for (int i = threadIdx.x; i < 512; i += 256) hist[i] = 0;
    __syncthreads();
    for (long long e = w0 + threadIdx.x; e < w1; e += 256) {
        int t = (e >= E) + (e >= 2LL * E);
        long long w = e - (long long)t * E;
        int dst = ei[(long long)t * 2 * E + E + w];
        atomicAdd(&hist[t * nbt + (dst >> BSH)], 1);
    }
    __syncthreads();
    for (int i = threadIdx.x; i < nbuk; i += 256) {
        int c = hist[i];
        base[i] = c ? atomicAdd(&bcur[i], c) : 0;
        hist[i] = 0;
    }
    __syncthreads();
    for (long long e = w0 + threadIdx.x; e < w1; e += 256) {
        int t = (e >= E) + (e >= 2LL * E);
        long long w = e - (long long)t * E;
        int src = ei[(long long)t * 2 * E + w];
        int dst = ei[(long long)t * 2 * E + E + w];
        int b = t * nbt + (dst >> BSH);
        int off = atomicAdd(&hist[b], 1);
        pairs[base[b] + off] = (uint32_t)src | ((uint32_t)(dst & ((1 << BSH) - 1)) << 22);
    }
}

// pass D: per-bucket counting sort -> rowstart, dinv, csr
__global__ __launch_bounds__(256) void k_bucket(const uint32_t* __restrict__ pairs,
                                                const int* __restrict__ bbase,
                                                int* __restrict__ rowstart,
                                                float* __restrict__ dinv,
                                                int* __restrict__ csr,
                                                int N, int nbt, int nbuk, int L) {
    __shared__ int cnt[1024];
    __shared__ int pref[1024];
    __shared__ int sums[256];
    int b = blockIdx.x;
    int t = b / nbt, bb = b - t * nbt;
    int dst0 = bb << BSH;
    int ndst = (N - dst0 < 1024) ? (N - dst0) : 1024;
    int e0 = bbase[b], e1 = bbase[b + 1];
    int tid = threadIdx.x;
    for (int i = tid; i < 1024; i += 256) cnt[i] = 0;
    __syncthreads();
    for (int e = e0 + tid; e < e1; e += 256) atomicAdd(&cnt[pairs[e] >> 22], 1);
    __syncthreads();
    int i0 = tid * 4;
    int c0 = cnt[i0], c1 = cnt[i0 + 1], c2 = cnt[i0 + 2], c3 = cnt[i0 + 3];
    int s4 = c0 + c1 + c2 + c3;
    sums[tid] = s4;
    __syncthreads();
    for (int off = 1; off < 256; off <<= 1) {
        int v = (tid >= off) ? sums[tid - off] : 0;
        __syncthreads();
        sums[tid] += v;
        __syncthreads();
    }
    int run = sums[tid] - s4;
    pref[i0] = run; run += c0;
    pref[i0 + 1] = run; run += c1;
    pref[i0 + 2] = run; run += c2;
    pref[i0 + 3] = run;
    __syncthreads();
    for (int d = tid; d < ndst; d += 256) {
        int r = t * N + dst0 + d;
        rowstart[r] = e0 + pref[d];
        dinv[r] = rsqrtf((float)cnt[d] + 1.0f);
    }
    if (b == nbuk - 1 && tid == 0) rowstart[L] = e1;
    __syncthreads();
    for (int e = e0 + tid; e < e1; e += 256) {
        uint32_t u = pairs[e];
        int d = u >> 22;
        int pos = e0 + atomicAdd(&pref[d], 1);
        csr[pos] = (int)(u & ((1u << 22) - 1));
    }
}

// CSR-aligned edge weights for layer-1: w16[e] = (f16)dinv_t[src_e]
__global__ void k_wedge(const int* __restrict__ csr, const float* __restrict__ dinv,
                        f16* __restrict__ w16, int N, int E) {
    long long tot = 3LL * E;
    long long i = (long long)blockIdx.x * 256 + threadIdx.x;
    long long st = (long long)gridDim.x * 256;
    for (; i < tot; i += st) {
        int t = (i >= E) + (i >= 2LL * E);
        w16[i] = (f16)dinv[t * N + csr[i]];
    }
}

// ---------------- MFMA GEMM: out(f16) = [relu](in @ W [+ bias]) [* scale[row]] ----------------
__global__ __launch_bounds__(256) void k_mgemm(const void* __restrict__ in, int in_f32,
                                               const f16* __restrict__ Wt,
                                               const float* __restrict__ bias,
                                               const float* __restrict__ scale,
                                               f16* __restrict__ outh, int n, int relu) {
    int l = threadIdx.x & 63, wid = threadIdx.x >> 6;
    int row0 = blockIdx.x * 64 + wid * 16;
    int r = l & 15, kg = l >> 4;
    int arow = row0 + r;
    f32x4 acc[8] = {};
#pragma unroll
    for (int kk = 0; kk < 4; kk++) {
        int off = kk * 32 + kg * 8;
        f16x8 a = {};
        if (arow < n) {
            if (in_f32) {
                const float* inf = (const float*)in + (size_t)arow * D_ + off;
                float4 v0 = *(const float4*)inf;
                float4 v1 = *(const float4*)(inf + 4);
                a[0] = (f16)v0.x; a[1] = (f16)v0.y; a[2] = (f16)v0.z; a[3] = (f16)v0.w;
                a[4] = (f16)v1.x; a[5] = (f16)v1.y; a[6] = (f16)v1.z; a[7] = (f16)v1.w;
            } else {
                a = *(const f16x8*)((const f16*)in + (size_t)arow * D_ + off);
            }
        }
#pragma unroll
        for (int ct = 0; ct < 8; ct++) {
            int c = ct * 16 + r;
            f16x8 b = *(const f16x8*)(Wt + (size_t)c * D_ + off);
            acc[ct] = __builtin_amdgcn_mfma_f32_16x16x32_f16(a, b, acc[ct], 0, 0, 0);
        }
    }
    float sc[4];
#pragma unroll
    for (int j = 0; j < 4; j++) {
        int rr = row0 + kg * 4 + j;
        sc[j] = (scale && rr < n) ? scale[rr] : 1.0f;
    }
#pragma unroll
    for (int ct = 0; ct < 8; ct++) {
        int c = ct * 16 + r;
        float bs = bias ? bias[c] : 0.0f;
#pragma unroll
        for (int j = 0; j < 4; j++) {
            int rr = row0 + kg * 4 + j;
            if (rr >= n) continue;
            float o = acc[ct][j] + bs;
            if (relu) o = fmaxf(o, 0.0f);
            o *= sc[j];
            outh[(size_t)rr * D_ + c] = (f16)o;
        }
    }
}

// ---------------- MFMA semantic attention: sum_r q . tanh(z_r @ Wsem + bsem) ----------------
__global__ __launch_bounds__(256) void k_matt(const f16* __restrict__ z,
                                              const f16* __restrict__ Wst,
                                              const float* __restrict__ bsem,
                                              const float* __restrict__ q,
                                              float* __restrict__ att_part, int n, int ttype) {
    int l = threadIdx.x & 63, wid = threadIdx.x >> 6;
    int row0 = blockIdx.x * 64 + wid * 16;
    int r = l & 15, kg = l >> 4;
    int arow = row0 + r;
    f32x4 acc[8] = {};
#pragma unroll
    for (int kk = 0; kk < 4; kk++) {
        int off = kk * 32 + kg * 8;
        f16x8 a = {};
        if (arow < n) a = *(const f16x8*)(z + (size_t)arow * D_ + off);
#pragma unroll
        for (int ct = 0; ct < 8; ct++) {
            int c = ct * 16 + r;
            f16x8 b = *(const f16x8*)(Wst + (size_t)c * D_ + off);
            acc[ct] = __builtin_amdgcn_mfma_f32_16x16x32_f16(a, b, acc[ct], 0, 0, 0);
        }
    }
    float s = 0.0f;
#pragma unroll
    for (int ct = 0; ct < 8; ct++) {
        int c = ct * 16 + r;
        float qc = q[c], bc = bsem[c];
#pragma unroll
        for (int j = 0; j < 4; j++) {
            int rr = row0 + kg * 4 + j;
            if (rr < n) s += qc * tanhf(acc[ct][j] + bc);
        }
    }
#pragma unroll
    for (int m = 1; m < 64; m <<= 1) s += __shfl_xor(s, m, 64);
    __shared__ float ws[4];
    if (l == 0) ws[wid] = s;
    __syncthreads();
    if (threadIdx.x == 0)
        atomicAdd(&att_part[((blockIdx.x & 63) << 2) + ttype], ws[0] + ws[1] + ws[2] + ws[3]);
}

// ---------------- GCN aggregate, batched over 3 types (rows = 3N), quarter-wave ----------------
// lanes split into 4 groups of 16; group g handles edges j+4g..j+4g+3; each lane loads 8 f16.
// edge_dinv=1: weight from w16 stream (dinv_t[src]);  edge_dinv=0: pre-scaled rows, w=1.
__global__ __launch_bounds__(256) void k_spmm(const f16* __restrict__ gsrc,
                                              const int* __restrict__ csr,
                                              const f16* __restrict__ w16,
                                              const int* __restrict__ rowstart,
                                              const float* __restrict__ dinv,
                                              const float* __restrict__ bias,
                                              f16* __restrict__ outh,
                                              int N, int rows, int edge_dinv, int src_typed) {
    int gw = (int)((blockIdx.x * (long long)blockDim.x + threadIdx.x) >> 6);
    int l = threadIdx.x & 63;
    if (gw >= rows) return;
    int qw = l >> 4, lp = l & 15;
    int t = gw / N;
    int tbase = t * N;
    int sbase = src_typed ? tbase : 0;
    int self = src_typed ? gw : (gw - tbase);
    int s0 = rowstart[gw], s1 = rowstart[gw + 1];
    float di = dinv[gw];
    size_t co = (size_t)(lp << 3);
    float a0 = 0.f, a1 = 0.f, a2 = 0.f, a3 = 0.f, a4 = 0.f, a5 = 0.f, a6 = 0.f, a7 = 0.f;
    if (qw == 0) {
        f16x8 sv = *(const f16x8*)(gsrc + (size_t)self * D_ + co);
        float wsf = edge_dinv ? di : 1.0f;
        a0 = (float)sv[0] * wsf; a1 = (float)sv[1] * wsf;
        a2 = (float)sv[2] * wsf; a3 = (float)sv[3] * wsf;
        a4 = (float)sv[4] * wsf; a5 = (float)sv[5] * wsf;
        a6 = (float)sv[6] * wsf; a7 = (float)sv[7] * wsf;
    }
    int j = s0;
    if (edge_dinv) {
        for (; j + 16 <= s1; j += 16) {
            int4 iv = *(const int4*)(csr + j + (qw << 2));
            h4v wv = *(const h4v*)(w16 + j + (qw << 2));
            float w0 = (float)wv[0], w1 = (float)wv[1], w2 = (float)wv[2], w3 = (float)wv[3];
            f16x8 v0 = *(const f16x8*)(gsrc + (size_t)(sbase + iv.x) * D_ + co);
            f16x8 v1 = *(const f16x8*)(gsrc + (size_t)(sbase + iv.y) * D_ + co);
            f16x8 v2 = *(const f16x8*)(gsrc + (size_t)(sbase + iv.z) * D_ + co);
            f16x8 v3 = *(const f16x8*)(gsrc + (size_t)(sbase + iv.w) * D_ + co);
            a0 = fmaf((float)v0[0], w0, a0); a1 = fmaf((float)v0[1], w0, a1);
            a2 = fmaf((float)v0[2], w0, a2); a3 = fmaf((float)v0[3], w0, a3);
            a4 = fmaf((float)v0[4], w0, a4); a5 = fmaf((float)v0[5], w0, a5);
            a6 = fmaf((float)v0[6], w0, a6); a7 = fmaf((float)v0[7], w0, a7);
            a0 = fmaf((float)v1[0], w1, a0); a1 = fmaf((float)v1[1], w1, a1);
            a2 = fmaf((float)v1[2], w1, a2); a3 = fmaf((float)v1[3], w1, a3);
            a4 = fmaf((float)v1[4], w1, a4); a5 = fmaf((float)v1[5], w1, a5);
            a6 = fmaf((float)v1[6], w1, a6); a7 = fmaf((float)v1[7], w1, a7);
            a0 = fmaf((float)v2[0], w2, a0); a1 = fmaf((float)v2[1], w2, a1);
            a2 = fmaf((float)v2[2], w2, a2); a3 = fmaf((float)v2[3], w2, a3);
            a4 = fmaf((float)v2[4], w2, a4); a5 = fmaf((float)v2[5], w2, a5);
            a6 = fmaf((float)v2[6], w2, a6); a7 = fmaf((float)v2[7], w2, a7);
            a0 = fmaf((float)v3[0], w3, a0); a1 = fmaf((float)v3[1], w3, a1);
            a2 = fmaf((float)v3[2], w3, a2); a3 = fmaf((float)v3[3], w3, a3);
            a4 = fmaf((float)v3[4], w3, a4); a5 = fmaf((float)v3[5], w3, a5);
            a6 = fmaf((float)v3[6], w3, a6); a7 = fmaf((float)v3[7], w3, a7);
        }
#pragma unroll
        for (int u = 0; u < 4; u++) {
            int e = j + (qw << 2) + u;
            if (e < s1) {
                int s = csr[e];
                float w = (float)w16[e];
                f16x8 v = *(const f16x8*)(gsrc + (size_t)(sbase + s) * D_ + co);
                a0 = fmaf((float)v[0], w, a0); a1 = fmaf((float)v[1], w, a1);
                a2 = fmaf((float)v[2], w, a2); a3 = fmaf((float)v[3], w, a3);
                a4 = fmaf((float)v[4], w, a4); a5 = fmaf((float)v[5], w, a5);
                a6 = fmaf((float)v[6], w, a6); a7 = fmaf((float)v[7], w, a7);
            }
        }
    } else {
        for (; j + 16 <= s1; j += 16) {
            int4 iv = *(const int4*)(csr + j + (qw << 2));
            f16x8 v0 = *(const f16x8*)(gsrc + (size_t)(sbase + iv.x) * D_ + co);
            f16x8 v1 = *(const f16x8*)(gsrc + (size_t)(sbase + iv.y) * D_ + co);
            f16x8 v2 = *(const f16x8*)(gsrc + (size_t)(sbase + iv.z) * D_ + co);
            f16x8 v3 = *(const f16x8*)(gsrc + (size_t)(sbase + iv.w) * D_ + co);
            a0 += (float)v0[0] + (float)v1[0] + (float)v2[0] + (float)v3[0];
            a1 += (float)v0[1] + (float)v1[1] + (float)v2[1] + (float)v3[1];
            a2 += (float)v0[2] + (float)v1[2] + (float)v2[2] + (float)v3[2];
            a3 += (float)v0[3] + (float)v1[3] + (float)v2[3] + (float)v3[3];
            a4 += (float)v0[4] + (float)v1[4] + (float)v2[4] + (float)v3[4];
            a5 += (float)v0[5] + (float)v1[5] + (float)v2[5] + (float)v3[5];
            a6 += (float)v0[6] + (float)v1[6] + (float)v2[6] + (float)v3[6];
            a7 += (float)v0[7] + (float)v1[7] + (float)v2[7] + (float)v3[7];
        }
#pragma unroll
        for (int u = 0; u < 4; u++) {
            int e = j + (qw << 2) + u;
            if (e < s1) {
                int s = csr[e];
                f16x8 v = *(const f16x8*)(gsrc + (size_t)(sbase + s) * D_ + co);
                a0 += (float)v[0]; a1 += (float)v[1]; a2 += (float)v[2]; a3 += (float)v[3];
                a4 += (float)v[4]; a5 += (float)v[5]; a6 += (float)v[6]; a7 += (float)v[7];
            }
        }
    }
    a0 += __shfl_xor(a0, 16, 64); a0 += __shfl_xor(a0, 32, 64);
    a1 += __shfl_xor(a1, 16, 64); a1 += __shfl_xor(a1, 32, 64);
    a2 += __shfl_xor(a2, 16, 64); a2 += __shfl_xor(a2, 32, 64);
    a3 += __shfl_xor(a3, 16, 64); a3 += __shfl_xor(a3, 32, 64);
    a4 += __shfl_xor(a4, 16, 64); a4 += __shfl_xor(a4, 32, 64);
    a5 += __shfl_xor(a5, 16, 64); a5 += __shfl_xor(a5, 32, 64);
    a6 += __shfl_xor(a6, 16, 64); a6 += __shfl_xor(a6, 32, 64);
    a7 += __shfl_xor(a7, 16, 64); a7 += __shfl_xor(a7, 32, 64);
    if (qw == 0) {
        float4 b0 = *(const float4*)(bias + co);
        float4 b1 = *(const float4*)(bias + co + 4);
        f16x8 o;
        o[0] = (f16)fmaxf(fmaf(a0, di, b0.x), 0.f);
        o[1] = (f16)fmaxf(fmaf(a1, di, b0.y), 0.f);
        o[2] = (f16)fmaxf(fmaf(a2, di, b0.z), 0.f);
        o[3] = (f16)fmaxf(fmaf(a3, di, b0.w), 0.f);
        o[4] = (f16)fmaxf(fmaf(a4, di, b1.x), 0.f);
        o[5] = (f16)fmaxf(fmaf(a5, di, b1.y), 0.f);
        o[6] = (f16)fmaxf(fmaf(a6, di, b1.z), 0.f);
        o[7] = (f16)fmaxf(fmaf(a7, di, b1.w), 0.f);
        *(f16x8*)(outh + (size_t)gw * D_ + co) = o;
    }
}

__global__ void k_attw(const float* __restrict__ att_part, float* __restrict__ att_w, float invN) {
    __shared__ float sb[3];
    int t = threadIdx.x;
    if (t < 3) {
        float s = 0.f;
        for (int i = 0; i < 64; i++) s += att_part[(i << 2) + t];
        sb[t] = s * invN;
    }
    __syncthreads();
    if (t == 0) {
        float m = fmaxf(sb[0], fmaxf(sb[1], sb[2]));
        float x0 = expf(sb[0] - m), x1 = expf(sb[1] - m), x2 = expf(sb[2] - m);
        float inv = 1.f / (x0 + x1 + x2);
        att_w[0] = x0 * inv; att_w[1] = x1 * inv; att_w[2] = x2 * inv;
    }
}

// ---------------- pos: column sums of combined rows (Z fp16, typed slices) ----------------
__global__ __launch_bounds__(256) void k_colsum(const f16* __restrict__ Z, size_t tstride,
                                                const float* __restrict__ att_w,
                                                float* __restrict__ colsum) {
    int c2 = threadIdx.x & 63;
    int rg = threadIdx.x >> 6;
    int nbase = blockIdx.x << 7;
    float w0 = att_w[0], w1 = att_w[1], w2 = att_w[2];
    float csx = 0.f, csy = 0.f;
    for (int i = rg; i < 128; i += 4) {
        size_t off = (size_t)(nbase + i) * D_ + (c2 << 1);
        h2v z0 = *(const h2v*)(Z + off);
        h2v z1 = *(const h2v*)(Z + tstride + off);
        h2v z2 = *(const h2v*)(Z + 2 * tstride + off);
        csx += w0 * (float)z0.x + w1 * (float)z1.x + w2 * (float)z2.x;
        csy += w0 * (float)z0.y + w1 * (float)z1.y + w2 * (float)z2.y;
    }
    __shared__ float red[4][128];
    red[rg][c2 << 1] = csx;
    red[rg][(c2 << 1) + 1] = csy;
    __syncthreads();
    if (rg == 0) {
        float sx = red[0][c2 << 1] + red[1][c2 << 1] + red[2][c2 << 1] + red[3][c2 << 1];
        float sy = red[0][(c2 << 1) + 1] + red[1][(c2 << 1) + 1] + red[2][(c2 << 1) + 1] + red[3][(c2 << 1) + 1];
        atomicAdd(&colsum[c2 << 1], sx);
        atomicAdd(&colsum[(c2 << 1) + 1], sy);
    }
}

__global__ void k_summary_c(const float* __restrict__ colsum, const float* __restrict__ sv,
                            const float* __restrict__ Wd, float* __restrict__ cvec,
                            float* __restrict__ out_summary) {
    __shared__ float sl[128];
    int t = threadIdx.x;
    float s = 0.5f * (sv[t] + colsum[t] * (1.0f / (float)BATCH_));
    sl[t] = s;
    out_summary[t] = s;
    __syncthreads();
    float a = 0.f;
    for (int j = 0; j < 128; j++) a = fmaf(Wd[t * D_ + j], sl[j], a);
    cvec[t] = a;
}

__global__ __launch_bounds__(256) void k_cscore(const f16* __restrict__ Z, size_t tstride,
                                                const float* __restrict__ att_w,
                                                const float* __restrict__ c,
                                                const float* __restrict__ bd,
                                                float* __restrict__ out, int B) {
    int gw = (int)((blockIdx.x * (long long)blockDim.x + threadIdx.x) >> 6);
    int lane = threadIdx.x & 63;
    if (gw >= B) return;
    size_t off = (size_t)gw * D_ + (lane << 1);
    float w0 = att_w[0], w1 = att_w[1], w2 = att_w[2];
    h2v z0 = *(const h2v*)(Z + off);
    h2v z1 = *(const h2v*)(Z + tstride + off);
    h2v z2 = *(const h2v*)(Z + 2 * tstride + off);
    float vx = w0 * (float)z0.x + w1 * (float)z1.x + w2 * (float)z2.x;
    float vy = w0 * (float)z0.y + w1 * (float)z1.y + w2 * (float)z2.y;
    float2 cc = *(const float2*)(c + (lane << 1));
    float a = vx * cc.x + vy * cc.y;
#pragma unroll
    for (int m = 1; m < 64; m <<= 1) a += __shfl_xor(a, m, 64);
    if (lane == 0) out[gw] = a + bd[0];
}

// ---------------- host launcher ----------------
extern "C" void kernel_launch(void* const* d_in, const int* in_sizes, int n_in,
                              void* d_out, int out_size, void* d_ws, size_t ws_size,
                              hipStream_t stream) {
    const float* x      = (const float*)d_in[0];
    const int*   ei     = (const int*)d_in[1];
    const int*   perm   = (const int*)d_in[2];
    const float* sv     = (const float*)d_in[3];
    const float* W_lin  = (const float*)d_in[5];
    const float* b_lin  = (const float*)d_in[6];
    const float* W1     = (const float*)d_in[7];
    const float* b1     = (const float*)d_in[8];
    const float* W2     = (const float*)d_in[9];
    const float* b2     = (const float*)d_in[10];
    const float* W_sem  = (const float*)d_in[11];
    const float* b_sem  = (const float*)d_in[12];
    const float* q_sem  = (const float*)d_in[13];
    const float* W_disc = (const float*)d_in[14];
    const float* b_disc = (const float*)d_in[15];
    float* out = (float*)d_out;

    int N = in_sizes[0] / D_;
    int E = in_sizes[1] / 6;
    int L = 3 * N;
    size_t ND = (size_t)N * D_;
    int B = BATCH_;
    int nbt = (N + (1 << BSH) - 1) >> BSH;
    int nbuk = 3 * nbt;

    char* ws = (char*)d_ws;
    size_t o = 0;
    auto alloc = [&](size_t bytes) -> char* {
        char* p = ws + o;
        o = (o + bytes + 255) & ~(size_t)255;
        return p;
    };
    float* dinv     = (float*)alloc((size_t)L * 4);
    int*   rowstart = (int*)alloc(((size_t)L + 1) * 4);
    int*   csr      = (int*)alloc(((size_t)3 * E + 16) * 4);
    int*   bcnt     = (int*)alloc(512 * 4);
    int*   bbase    = (int*)alloc(513 * 4);
    int*   bcur     = (int*)alloc(512 * 4);
    float* att_part = (float*)alloc(256 * 4);
    float* att_w    = (float*)alloc(16 * 4);
    float* colsum   = (float*)alloc(128 * 4);
    float* cvec     = (float*)alloc(128 * 4);
    f16*   Wlt      = (f16*)alloc(128 * 128 * 2);
    f16*   W1t      = (f16*)alloc(128 * 128 * 2);
    f16*   W2t      = (f16*)alloc(128 * 128 * 2);
    f16*   Wst      = (f16*)alloc(128 * 128 * 2);
    f16*   Ah       = (f16*)alloc(ND * 2);        // relu(x@Wlin+b); reused later as w16
    f16*   G1h      = (f16*)alloc(ND * 2);
    f16*   G1p      = (f16*)alloc(ND * 2);
    f16*   H1all    = (f16*)alloc(3 * ND * 2);    // h1 (3 types), in-place G2
    f16*   Zall     = (f16*)alloc(3 * ND * 2);    // z (3 types); front reused as pairs
    size_t o_full = o;

    uint32_t* pairs = (uint32_t*)Zall;            // 3E*4 <= 3*ND*2 bytes
    f16*      w16  = (f16*)Ah;                    // 3E*2 <= ND*2 bytes (E<=N*D/... checked below)

    if (o_full > ws_size || N >= (1 << 22) || nbuk > 512 ||
        (size_t)3 * E * 4 > 3 * ND * 2 || (size_t)3 * E * 2 > ND * 2) {
        k_sentinel<<<256, 256, 0, stream>>>(out, out_size);
        return;
    }

    // weight transposes (f32 -> f16, [c][k])
    k_wt<<<64, 256, 0, stream>>>(W_lin, Wlt);
    k_wt<<<64, 256, 0, stream>>>(W1, W1t);
    k_wt<<<64, 256, 0, stream>>>(W2, W2t);
    k_wt<<<64, 256, 0, stream>>>(W_sem, Wst);

    // ---- bucketed CSR build ----
    long long tot = 3LL * E;
    k_zero32<<<2, 256, 0, stream>>>((uint32_t*)bcnt, 512);
    k_hist<<<2048, 256, 0, stream>>>(ei, bcnt, E, nbt, nbuk);
    k_bscan<<<1, 512, 0, stream>>>(bcnt, bbase, bcur, nbuk);
    int scat_grid = (int)((tot + TILE_ - 1) / TILE_);
    k_scatter<<<scat_grid, 256, 0, stream>>>(ei, bcur, pairs, E, nbt, nbuk);
    k_bucket<<<nbuk, 256, 0, stream>>>(pairs, bbase, rowstart, dinv, csr, N, nbt, nbuk, L);

    int mgN_grid  = (N + 63) / 64;
    int mgL_grid  = (L + 63) / 64;
    int spmm_grid = (L + 3) / 4;
    int scoreB_grid = (B + 3) / 4;

    // shared: A = relu(x@Wlin+b);  G1 = A@W1;  G1p = G1[perm];  then Ah becomes w16
    k_mgemm<<<mgN_grid, 256, 0, stream>>>(x, 1, Wlt, b_lin, nullptr, Ah, N, 1);
    k_mgemm<<<mgN_grid, 256, 0, stream>>>(Ah, 0, W1t, nullptr, nullptr, G1h, N, 0);
    k_gath<<<(N * 64 + 255) / 256, 256, 0, stream>>>((const uint32_t*)G1h, perm,
                                                     (uint32_t*)G1p, N);
    k_wedge<<<2048, 256, 0, stream>>>(csr, dinv, w16, N, E);   // overwrites Ah (dead)

    for (int br = 0; br < 2; br++) {
        const f16* src1 = br ? G1p : G1h;
        float* aw = att_w + br * 8;
        k_zero32<<<1, 256, 0, stream>>>((uint32_t*)att_part, 256);
        // h1 (all 3 types)
        k_spmm<<<spmm_grid, 256, 0, stream>>>(src1, csr, w16, rowstart, dinv, b1,
                                              H1all, N, L, 1, 0);
        // G2 = (h1 @ W2) * dinv  (in-place, all 3 types)
        k_mgemm<<<mgL_grid, 256, 0, stream>>>(H1all, 0, W2t, nullptr, dinv, H1all, L, 0);
        // z (all 3 types)
        k_spmm<<<spmm_grid, 256, 0, stream>>>(H1all, csr, w16, rowstart, dinv, b2,
                                              Zall, N, L, 0, 1);
        for (int t3 = 0; t3 < 3; t3++)
            k_matt<<<mgN_grid, 256, 0, stream>>>(Zall + (size_t)t3 * ND, Wst, b_sem, q_sem,
                                                 att_part, N, t3);
        k_attw<<<1, 64, 0, stream>>>(att_part, aw, 1.0f / (float)N);
        if (br == 0) {
            k_zero32<<<1, 256, 0, stream>>>((uint32_t*)colsum, 128);
            k_colsum<<<512, 256, 0, stream>>>(Zall, ND, aw, colsum);
            k_summary_c<<<1, 128, 0, stream>>>(colsum, sv, W_disc, cvec, out + 2 * (size_t)B);
            k_cscore<<<scoreB_grid, 256, 0, stream>>>(Zall, ND, aw, cvec, b_disc, out, B);
        } else {
            k_cscore<<<scoreB_grid, 256, 0, stream>>>(Zall, ND, aw, cvec, b_disc, out + B, B);
        }
    }
}

// Round 8
// 1495.225 us; speedup vs baseline: 2.6733x; 1.1626x over previous
//
#include <hip/hip_runtime.h>

#define D_ 128
#define BATCH_ 65536
#define BSH 10          // bucket = 1024 destinations
#define TILE_ 16384     // edges per scatter block

typedef _Float16 f16;
typedef _Float16 h2v __attribute__((ext_vector_type(2)));
typedef _Float16 h4v __attribute__((ext_vector_type(4)));
typedef _Float16 f16x8 __attribute__((ext_vector_type(8)));
typedef float f32x4 __attribute__((ext_vector_type(4)));

// ---------------- utility ----------------
__global__ void k_zero32(uint32_t* p, long long n) {
    long long i = (long long)blockIdx.x * blockDim.x + threadIdx.x;
    long long st = (long long)gridDim.x * blockDim.x;
    for (; i < n; i += st) p[i] = 0u;
}

__global__ void k_sentinel(float* p, long long n) {
    long long i = (long long)blockIdx.x * blockDim.x + threadIdx.x;
    long long st = (long long)gridDim.x * blockDim.x;
    for (; i < n; i += st) p[i] = -12345.0f;
}

// transpose+convert 128x128 weight: Wt[c][k] = (f16)W[k][c]
__global__ void k_wt(const float* __restrict__ W, f16* __restrict__ Wt) {
    int t = blockIdx.x * 256 + threadIdx.x;
    int k = t >> 7, c = t & 127;
    Wt[c * 128 + k] = (f16)W[k * 128 + c];
}

// row gather: dst[i][:] = src[perm[i]][:]   (fp16 rows as u32 pairs)
__global__ void k_gath(const uint32_t* __restrict__ src, const int* __restrict__ perm,
                       uint32_t* __restrict__ dst, int N) {
    int i = blockIdx.x * 256 + threadIdx.x;
    if (i >= N * 64) return;
    int row = i >> 6, col = i & 63;
    dst[i] = src[((size_t)perm[row] << 6) + col];
}

// ---------------- bucketed CSR build ----------------
__global__ void k_hist(const int* __restrict__ ei, int* __restrict__ bcnt,
                       int E, int nbt, int nbuk) {
    __shared__ int hist[512];
    for (int i = threadIdx.x; i < 512; i += 256) hist[i] = 0;
    __syncthreads();
    long long tot = 3LL * E;
    long long i = (long long)blockIdx.x * 256 + threadIdx.x;
    long long st = (long long)gridDim.x * 256;
    for (; i < tot; i += st) {
        int t = (i >= E) + (i >= 2LL * E);
        long long w = i - (long long)t * E;
        int dst = ei[(long long)t * 2 * E + E + w];
        atomicAdd(&hist[t * nbt + (dst >> BSH)], 1);
    }
    __syncthreads();
    for (int i2 = threadIdx.x; i2 < nbuk; i2 += 256)
        if (hist[i2]) atomicAdd(&bcnt[i2], hist[i2]);
}

__global__ void k_bscan(const int* __restrict__ bcnt, int* __restrict__ bbase,
                        int* __restrict__ bcur, int nbuk) {
    __shared__ int s[512];
    int t = threadIdx.x;
    int v = (t < nbuk) ? bcnt[t] : 0;
    s[t] = v;
    __syncthreads();
    for (int off = 1; off < 512; off <<= 1) {
        int a = (t >= off) ? s[t - off] : 0;
        __syncthreads();
        s[t] += a;
        __syncthreads();
    }
    if (t < nbuk) {
        int e = s[t] - v;
        bbase[t] = e;
        bcur[t] = e;
        if (t == nbuk - 1) bbase[nbuk] = s[t];
    }
}

__global__ __launch_bounds__(256) void k_scatter(const int* __restrict__ ei,
                                                 int* __restrict__ bcur,
                                                 uint32_t* __restrict__ pairs,
                                                 int E, int nbt, int nbuk) {
    __shared__ int hist[512];
    __shared__ int base[512];
    long long tot = 3LL * E;
    long long w0 = (long long)blockIdx.x * TILE_;
    long long w1 = w0 + TILE_ < tot ? w0 + TILE_ : tot;
    for (int i = threadIdx.x; i < 512; i += 256) hist[i] = 0;
    __syncthreads();
    for (long long e = w0 + threadIdx.x; e < w1; e += 256) {
        int t = (e >= E) + (e >= 2LL * E);
        long long w = e - (long long)t * E;
        int dst = ei[(long long)t * 2 * E + E + w];
        atomicAdd(&hist[t * nbt + (dst >> BSH)], 1);
    }
    __syncthreads();
    for (int i = threadIdx.x; i < nbuk; i += 256) {
        int c = hist[i];
        base[i] = c ? atomicAdd(&bcur[i], c) : 0;
        hist[i] = 0;
    }
    __syncthreads();
    for (long long e = w0 + threadIdx.x; e < w1; e += 256) {
        int t = (e >= E) + (e >= 2LL * E);
        long long w = e - (long long)t * E;
        int src = ei[(long long)t * 2 * E + w];
        int dst = ei[(long long)t * 2 * E + E + w];
        int b = t * nbt + (dst >> BSH);
        int off = atomicAdd(&hist[b], 1);
        pairs[base[b] + off] = (uint32_t)src | ((uint32_t)(dst & ((1 << BSH) - 1)) << 22);
    }
}

__global__ __launch_bounds__(256) void k_bucket(const uint32_t* __restrict__ pairs,
                                                const int* __restrict__ bbase,
                                                int* __restrict__ rowstart,
                                                float* __restrict__ dinv,
                                                int* __restrict__ csr,
                                                int N, int nbt, int nbuk, int L) {
    __shared__ int cnt[1024];
    __shared__ int pref[1024];
    __shared__ int sums[256];
    int b = blockIdx.x;
    int t = b / nbt, bb = b - t * nbt;
    int dst0 = bb << BSH;
    int ndst = (N - dst0 < 1024) ? (N - dst0) : 1024;
    int e0 = bbase[b], e1 = bbase[b + 1];
    int tid = threadIdx.x;
    for (int i = tid; i < 1024; i += 256) cnt[i] = 0;
    __syncthreads();
    for (int e = e0 + tid; e < e1; e += 256) atomicAdd(&cnt[pairs[e] >> 22], 1);
    __syncthreads();
    int i0 = tid * 4;
    int c0 = cnt[i0], c1 = cnt[i0 + 1], c2 = cnt[i0 + 2], c3 = cnt[i0 + 3];
    int s4 = c0 + c1 + c2 + c3;
    sums[tid] = s4;
    __syncthreads();
    for (int off = 1; off < 256; off <<= 1) {
        int v = (tid >= off) ? sums[tid - off] : 0;
        __syncthreads();
        sums[tid] += v;
        __syncthreads();
    }
    int run = sums[tid] - s4;
    pref[i0] = run; run += c0;
    pref[i0 + 1] = run; run += c1;
    pref[i0 + 2] = run; run += c2;
    pref[i0 + 3] = run;
    __syncthreads();
    for (int d = tid; d < ndst; d += 256) {
        int r = t * N + dst0 + d;
        rowstart[r] = e0 + pref[d];
        dinv[r] = rsqrtf((float)cnt[d] + 1.0f);
    }
    if (b == nbuk - 1 && tid == 0) rowstart[L] = e1;
    __syncthreads();
    for (int e = e0 + tid; e < e1; e += 256) {
        uint32_t u = pairs[e];
        int d = u >> 22;
        int pos = e0 + atomicAdd(&pref[d], 1);
        csr[pos] = (int)(u & ((1u << 22) - 1));
    }
}

// CSR-aligned edge weights: w16[e] = (f16)dinv_t[src_e]  (valid for BOTH layers)
__global__ void k_wedge(const int* __restrict__ csr, const float* __restrict__ dinv,
                        f16* __restrict__ w16, int N, int E) {
    long long tot = 3LL * E;
    long long i = (long long)blockIdx.x * 256 + threadIdx.x;
    long long st = (long long)gridDim.x * 256;
    for (; i < tot; i += st) {
        int t = (i >= E) + (i >= 2LL * E);
        w16[i] = (f16)dinv[t * N + csr[i]];
    }
}

// ---------------- MFMA GEMM: out(f16) = [relu](in @ W [+ bias]) ----------------
__global__ __launch_bounds__(256) void k_mgemm(const void* __restrict__ in, int in_f32,
                                               const f16* __restrict__ Wt,
                                               const float* __restrict__ bias,
                                               f16* __restrict__ outh, int n, int relu) {
    int l = threadIdx.x & 63, wid = threadIdx.x >> 6;
    int row0 = blockIdx.x * 64 + wid * 16;
    int r = l & 15, kg = l >> 4;
    int arow = row0 + r;
    f32x4 acc[8] = {};
#pragma unroll
    for (int kk = 0; kk < 4; kk++) {
        int off = kk * 32 + kg * 8;
        f16x8 a = {};
        if (arow < n) {
            if (in_f32) {
                const float* inf = (const float*)in + (size_t)arow * D_ + off;
                float4 v0 = *(const float4*)inf;
                float4 v1 = *(const float4*)(inf + 4);
                a[0] = (f16)v0.x; a[1] = (f16)v0.y; a[2] = (f16)v0.z; a[3] = (f16)v0.w;
                a[4] = (f16)v1.x; a[5] = (f16)v1.y; a[6] = (f16)v1.z; a[7] = (f16)v1.w;
            } else {
                a = *(const f16x8*)((const f16*)in + (size_t)arow * D_ + off);
            }
        }
#pragma unroll
        for (int ct = 0; ct < 8; ct++) {
            int c = ct * 16 + r;
            f16x8 b = *(const f16x8*)(Wt + (size_t)c * D_ + off);
            acc[ct] = __builtin_amdgcn_mfma_f32_16x16x32_f16(a, b, acc[ct], 0, 0, 0);
        }
    }
#pragma unroll
    for (int ct = 0; ct < 8; ct++) {
        int c = ct * 16 + r;
        float bs = bias ? bias[c] : 0.0f;
#pragma unroll
        for (int j = 0; j < 4; j++) {
            int rr = row0 + kg * 4 + j;
            if (rr >= n) continue;
            float o = acc[ct][j] + bs;
            if (relu) o = fmaxf(o, 0.0f);
            outh[(size_t)rr * D_ + c] = (f16)o;
        }
    }
}

// ---------------- MFMA semantic attention: sum_r q . tanh(z_r @ Wsem + bsem) ----------------
__global__ __launch_bounds__(256) void k_matt(const f16* __restrict__ z,
                                              const f16* __restrict__ Wst,
                                              const float* __restrict__ bsem,
                                              const float* __restrict__ q,
                                              float* __restrict__ att_part, int n, int ttype) {
    int l = threadIdx.x & 63, wid = threadIdx.x >> 6;
    int row0 = blockIdx.x * 64 + wid * 16;
    int r = l & 15, kg = l >> 4;
    int arow = row0 + r;
    f32x4 acc[8] = {};
#pragma unroll
    for (int kk = 0; kk < 4; kk++) {
        int off = kk * 32 + kg * 8;
        f16x8 a = {};
        if (arow < n) a = *(const f16x8*)(z + (size_t)arow * D_ + off);
#pragma unroll
        for (int ct = 0; ct < 8; ct++) {
            int c = ct * 16 + r;
            f16x8 b = *(const f16x8*)(Wst + (size_t)c * D_ + off);
            acc[ct] = __builtin_amdgcn_mfma_f32_16x16x32_f16(a, b, acc[ct], 0, 0, 0);
        }
    }
    float s = 0.0f;
#pragma unroll
    for (int ct = 0; ct < 8; ct++) {
        int c = ct * 16 + r;
        float qc = q[c], bc = bsem[c];
#pragma unroll
        for (int j = 0; j < 4; j++) {
            int rr = row0 + kg * 4 + j;
            if (rr < n) s += qc * tanhf(acc[ct][j] + bc);
        }
    }
#pragma unroll
    for (int m = 1; m < 64; m <<= 1) s += __shfl_xor(s, m, 64);
    __shared__ float ws[4];
    if (l == 0) ws[wid] = s;
    __syncthreads();
    if (threadIdx.x == 0)
        atomicAdd(&att_part[((blockIdx.x & 63) << 2) + ttype], ws[0] + ws[1] + ws[2] + ws[3]);
}

// ---------------- GCN aggregate: one 16-lane group per row, no cross-lane reduce ----------------
// out[i] = relu( (Σ_j w16[e_j]*g[sbase+s_j] + di*g[self]) * di + bias )
// src_typed=0: g has N rows (layer-1, shared table);  =1: g has 3N rows (layer-2).
__global__ __launch_bounds__(256) void k_spmm(const f16* __restrict__ gsrc,
                                              const int* __restrict__ csr,
                                              const f16* __restrict__ w16,
                                              const int* __restrict__ rowstart,
                                              const float* __restrict__ dinv,
                                              const float* __restrict__ bias,
                                              f16* __restrict__ outh,
                                              int N, int rows, int src_typed) {
    int tid = (int)threadIdx.x;
    int lp = tid & 15;
    int gw = blockIdx.x * 16 + (tid >> 4);
    if (gw >= rows) return;
    int t = (gw >= N) + (gw >= 2 * N);
    int tbase = t * N;
    int sbase = src_typed ? tbase : 0;
    int self = src_typed ? gw : gw - tbase;
    int s0 = rowstart[gw], s1 = rowstart[gw + 1];
    float di = dinv[gw];
    size_t co = (size_t)(lp << 3);
    const f16* gp = gsrc + co;
    float a[8];
    {
        f16x8 sv = *(const f16x8*)(gp + (size_t)self * D_);
#pragma unroll
        for (int u = 0; u < 8; u++) a[u] = (float)sv[u] * di;
    }
    int j = s0;
    for (; j + 2 <= s1; j += 2) {
        int sA = csr[j], sB = csr[j + 1];
        float wA = (float)w16[j], wB = (float)w16[j + 1];
        f16x8 vA = *(const f16x8*)(gp + (size_t)(sbase + sA) * D_);
        f16x8 vB = *(const f16x8*)(gp + (size_t)(sbase + sB) * D_);
#pragma unroll
        for (int u = 0; u < 8; u++) a[u] = fmaf((float)vA[u], wA, a[u]);
#pragma unroll
        for (int u = 0; u < 8; u++) a[u] = fmaf((float)vB[u], wB, a[u]);
    }
    if (j < s1) {
        int s = csr[j];
        float w = (float)w16[j];
        f16x8 v = *(const f16x8*)(gp + (size_t)(sbase + s) * D_);
#pragma unroll
        for (int u = 0; u < 8; u++) a[u] = fmaf((float)v[u], w, a[u]);
    }
    float4 b0 = *(const float4*)(bias + co);
    float4 b1 = *(const float4*)(bias + co + 4);
    f16x8 o;
    o[0] = (f16)fmaxf(fmaf(a[0], di, b0.x), 0.f);
    o[1] = (f16)fmaxf(fmaf(a[1], di, b0.y), 0.f);
    o[2] = (f16)fmaxf(fmaf(a[2], di, b0.z), 0.f);
    o[3] = (f16)fmaxf(fmaf(a[3], di, b0.w), 0.f);
    o[4] = (f16)fmaxf(fmaf(a[4], di, b1.x), 0.f);
    o[5] = (f16)fmaxf(fmaf(a[5], di, b1.y), 0.f);
    o[6] = (f16)fmaxf(fmaf(a[6], di, b1.z), 0.f);
    o[7] = (f16)fmaxf(fmaf(a[7], di, b1.w), 0.f);
    *(f16x8*)(outh + (size_t)gw * D_ + co) = o;
}

__global__ void k_attw(const float* __restrict__ att_part, float* __restrict__ att_w, float invN) {
    __shared__ float sb[3];
    int t = threadIdx.x;
    if (t < 3) {
        float s = 0.f;
        for (int i = 0; i < 64; i++) s += att_part[(i << 2) + t];
        sb[t] = s * invN;
    }
    __syncthreads();
    if (t == 0) {
        float m = fmaxf(sb[0], fmaxf(sb[1], sb[2]));
        float x0 = expf(sb[0] - m), x1 = expf(sb[1] - m), x2 = expf(sb[2] - m);
        float inv = 1.f / (x0 + x1 + x2);
        att_w[0] = x0 * inv; att_w[1] = x1 * inv; att_w[2] = x2 * inv;
    }
}

// ---------------- pos: column sums of combined rows (Z fp16, typed slices) ----------------
__global__ __launch_bounds__(256) void k_colsum(const f16* __restrict__ Z, size_t tstride,
                                                const float* __restrict__ att_w,
                                                float* __restrict__ colsum) {
    int c2 = threadIdx.x & 63;
    int rg = threadIdx.x >> 6;
    int nbase = blockIdx.x << 7;
    float w0 = att_w[0], w1 = att_w[1], w2 = att_w[2];
    float csx = 0.f, csy = 0.f;
    for (int i = rg; i < 128; i += 4) {
        size_t off = (size_t)(nbase + i) * D_ + (c2 << 1);
        h2v z0 = *(const h2v*)(Z + off);
        h2v z1 = *(const h2v*)(Z + tstride + off);
        h2v z2 = *(const h2v*)(Z + 2 * tstride + off);
        csx += w0 * (float)z0.x + w1 * (float)z1.x + w2 * (float)z2.x;
        csy += w0 * (float)z0.y + w1 * (float)z1.y + w2 * (float)z2.y;
    }
    __shared__ float red[4][128];
    red[rg][c2 << 1] = csx;
    red[rg][(c2 << 1) + 1] = csy;
    __syncthreads();
    if (rg == 0) {
        float sx = red[0][c2 << 1] + red[1][c2 << 1] + red[2][c2 << 1] + red[3][c2 << 1];
        float sy = red[0][(c2 << 1) + 1] + red[1][(c2 << 1) + 1] + red[2][(c2 << 1) + 1] + red[3][(c2 << 1) + 1];
        atomicAdd(&colsum[c2 << 1], sx);
        atomicAdd(&colsum[(c2 << 1) + 1], sy);
    }
}

__global__ void k_summary_c(const float* __restrict__ colsum, const float* __restrict__ sv,
                            const float* __restrict__ Wd, float* __restrict__ cvec,
                            float* __restrict__ out_summary) {
    __shared__ float sl[128];
    int t = threadIdx.x;
    float s = 0.5f * (sv[t] + colsum[t] * (1.0f / (float)BATCH_));
    sl[t] = s;
    out_summary[t] = s;
    __syncthreads();
    float a = 0.f;
    for (int j = 0; j < 128; j++) a = fmaf(Wd[t * D_ + j], sl[j], a);
    cvec[t] = a;
}

__global__ __launch_bounds__(256) void k_cscore(const f16* __restrict__ Z, size_t tstride,
                                                const float* __restrict__ att_w,
                                                const float* __restrict__ c,
                                                const float* __restrict__ bd,
                                                float* __restrict__ out, int B) {
    int gw = (int)((blockIdx.x * (long long)blockDim.x + threadIdx.x) >> 6);
    int lane = threadIdx.x & 63;
    if (gw >= B) return;
    size_t off = (size_t)gw * D_ + (lane << 1);
    float w0 = att_w[0], w1 = att_w[1], w2 = att_w[2];
    h2v z0 = *(const h2v*)(Z + off);
    h2v z1 = *(const h2v*)(Z + tstride + off);
    h2v z2 = *(const h2v*)(Z + 2 * tstride + off);
    float vx = w0 * (float)z0.x + w1 * (float)z1.x + w2 * (float)z2.x;
    float vy = w0 * (float)z0.y + w1 * (float)z1.y + w2 * (float)z2.y;
    float2 cc = *(const float2*)(c + (lane << 1));
    float a = vx * cc.x + vy * cc.y;
#pragma unroll
    for (int m = 1; m < 64; m <<= 1) a += __shfl_xor(a, m, 64);
    if (lane == 0) out[gw] = a + bd[0];
}

// ---------------- host launcher ----------------
extern "C" void kernel_launch(void* const* d_in, const int* in_sizes, int n_in,
                              void* d_out, int out_size, void* d_ws, size_t ws_size,
                              hipStream_t stream) {
    const float* x      = (const float*)d_in[0];
    const int*   ei     = (const int*)d_in[1];
    const int*   perm   = (const int*)d_in[2];
    const float* sv     = (const float*)d_in[3];
    const float* W_lin  = (const float*)d_in[5];
    const float* b_lin  = (const float*)d_in[6];
    const float* W1     = (const float*)d_in[7];
    const float* b1     = (const float*)d_in[8];
    const float* W2     = (const float*)d_in[9];
    const float* b2     = (const float*)d_in[10];
    const float* W_sem  = (const float*)d_in[11];
    const float* b_sem  = (const float*)d_in[12];
    const float* q_sem  = (const float*)d_in[13];
    const float* W_disc = (const float*)d_in[14];
    const float* b_disc = (const float*)d_in[15];
    float* out = (float*)d_out;

    int N = in_sizes[0] / D_;
    int E = in_sizes[1] / 6;
    int L = 3 * N;
    size_t ND = (size_t)N * D_;
    int B = BATCH_;
    int nbt = (N + (1 << BSH) - 1) >> BSH;
    int nbuk = 3 * nbt;

    char* ws = (char*)d_ws;
    size_t o = 0;
    auto alloc = [&](size_t bytes) -> char* {
        char* p = ws + o;
        o = (o + bytes + 255) & ~(size_t)255;
        return p;
    };
    float* dinv     = (float*)alloc((size_t)L * 4);
    int*   rowstart = (int*)alloc(((size_t)L + 1) * 4);
    int*   csr      = (int*)alloc(((size_t)3 * E + 16) * 4);
    int*   bcnt     = (int*)alloc(512 * 4);
    int*   bbase    = (int*)alloc(513 * 4);
    int*   bcur     = (int*)alloc(512 * 4);
    float* att_part = (float*)alloc(256 * 4);
    float* att_w    = (float*)alloc(16 * 4);
    float* colsum   = (float*)alloc(128 * 4);
    float* cvec     = (float*)alloc(128 * 4);
    f16*   Wlt      = (f16*)alloc(128 * 128 * 2);
    f16*   W1t      = (f16*)alloc(128 * 128 * 2);
    f16*   W2t      = (f16*)alloc(128 * 128 * 2);
    f16*   Wst      = (f16*)alloc(128 * 128 * 2);
    f16*   Ah       = (f16*)alloc(ND * 2);        // relu(x@Wlin+b); reused later as w16
    f16*   G1h      = (f16*)alloc(ND * 2);
    f16*   G1p      = (f16*)alloc(ND * 2);
    f16*   H1all    = (f16*)alloc(3 * ND * 2);    // h1 (3 types), in-place G2 (unscaled)
    f16*   Zall     = (f16*)alloc(3 * ND * 2);    // z (3 types); front reused as pairs
    size_t o_full = o;

    uint32_t* pairs = (uint32_t*)Zall;
    f16*      w16  = (f16*)Ah;

    if (o_full > ws_size || N >= (1 << 22) || nbuk > 512 ||
        (size_t)3 * E * 4 > 3 * ND * 2 || (size_t)3 * E * 2 > ND * 2) {
        k_sentinel<<<256, 256, 0, stream>>>(out, out_size);
        return;
    }

    // weight transposes (f32 -> f16, [c][k])
    k_wt<<<64, 256, 0, stream>>>(W_lin, Wlt);
    k_wt<<<64, 256, 0, stream>>>(W1, W1t);
    k_wt<<<64, 256, 0, stream>>>(W2, W2t);
    k_wt<<<64, 256, 0, stream>>>(W_sem, Wst);

    // ---- bucketed CSR build ----
    long long tot = 3LL * E;
    k_zero32<<<2, 256, 0, stream>>>((uint32_t*)bcnt, 512);
    k_hist<<<2048, 256, 0, stream>>>(ei, bcnt, E, nbt, nbuk);
    k_bscan<<<1, 512, 0, stream>>>(bcnt, bbase, bcur, nbuk);
    int scat_grid = (int)((tot + TILE_ - 1) / TILE_);
    k_scatter<<<scat_grid, 256, 0, stream>>>(ei, bcur, pairs, E, nbt, nbuk);
    k_bucket<<<nbuk, 256, 0, stream>>>(pairs, bbase, rowstart, dinv, csr, N, nbt, nbuk, L);

    int mgN_grid  = (N + 63) / 64;
    int mgL_grid  = (L + 63) / 64;
    int spmm_grid = (L + 15) / 16;
    int scoreB_grid = (B + 3) / 4;

    // shared: A = relu(x@Wlin+b);  G1 = A@W1;  G1p = G1[perm];  then Ah becomes w16
    k_mgemm<<<mgN_grid, 256, 0, stream>>>(x, 1, Wlt, b_lin, Ah, N, 1);
    k_mgemm<<<mgN_grid, 256, 0, stream>>>(Ah, 0, W1t, nullptr, G1h, N, 0);
    k_gath<<<(N * 64 + 255) / 256, 256, 0, stream>>>((const uint32_t*)G1h, perm,
                                                     (uint32_t*)G1p, N);
    k_wedge<<<2048, 256, 0, stream>>>(csr, dinv, w16, N, E);   // overwrites Ah (dead)

    for (int br = 0; br < 2; br++) {
        const f16* src1 = br ? G1p : G1h;
        float* aw = att_w + br * 8;
        k_zero32<<<1, 256, 0, stream>>>((uint32_t*)att_part, 256);
        // h1 (all 3 types): src table = G1 (N rows, shared)
        k_spmm<<<spmm_grid, 256, 0, stream>>>(src1, csr, w16, rowstart, dinv, b1,
                                              H1all, N, L, 0);
        // G2 = h1 @ W2  (in-place, unscaled; w16 carries dinv[src])
        k_mgemm<<<mgL_grid, 256, 0, stream>>>(H1all, 0, W2t, nullptr, H1all, L, 0);
        // z (all 3 types): src table = G2 (3N rows, typed)
        k_spmm<<<spmm_grid, 256, 0, stream>>>(H1all, csr, w16, rowstart, dinv, b2,
                                              Zall, N, L, 1);
        for (int t3 = 0; t3 < 3; t3++)
            k_matt<<<mgN_grid, 256, 0, stream>>>(Zall + (size_t)t3 * ND, Wst, b_sem, q_sem,
                                                 att_part, N, t3);
        k_attw<<<1, 64, 0, stream>>>(att_part, aw, 1.0f / (float)N);
        if (br == 0) {
            k_zero32<<<1, 256, 0, stream>>>((uint32_t*)colsum, 128);
            k_colsum<<<512, 256, 0, stream>>>(Zall, ND, aw, colsum);
            k_summary_c<<<1, 128, 0, stream>>>(colsum, sv, W_disc, cvec, out + 2 * (size_t)B);
            k_cscore<<<scoreB_grid, 256, 0, stream>>>(Zall, ND, aw, cvec, b_disc, out, B);
        } else {
            k_cscore<<<scoreB_grid, 256, 0, stream>>>(Zall, ND, aw, cvec, b_disc, out + B, B);
        }
    }
}